// Round 7
// baseline (676.684 us; speedup 1.0000x reference)
//
#include <hip/hip_runtime.h>

// GCN: 3x (linear -> symmetric-norm conv -> bias -> tanh) -> linear.
// N=200000, E=3200000, F=256->32->16->8->4, fp32.
// Round 7: linear1 v3 — BM=256/BK=32, 128 threads, 8x8 register tile
// (rows rg+32i => broadcast-conflict-free b128 LDS reads), full-line
// coalesced staging, register-double-buffered async staging (T14),
// 45KB LDS => 3 blocks/CU, grid 782 = 3.05 blocks/CU. Rest = round 5.
// Algebra: norm = dinv[s]*dinv[d]  =>  agg_i = dinv_i * (hs_i + sum_in hs_src)
// with hs = (h @ W) * dinv computed in each linear's epilogue.

constexpr int F_IN = 256;
constexpr int BSH = 10;            // nodes per coarse bucket = 1024
constexpr int BN  = 1 << BSH;
constexpr int CH  = 8192;          // edges per chunk

// ---- pass A1: per-chunk bucket histogram (transposed store: hist[b][c]) ----
__global__ void histc_kernel(const int* __restrict__ dst, int* __restrict__ hist,
                             int NB_C, int nch, int E) {
    __shared__ int h[256];
    const int t = threadIdx.x, c = blockIdx.x;
    h[t] = 0; __syncthreads();
    const int e0 = c * CH, e1 = min(e0 + CH, E);
    for (int e = e0 + t; e < e1; e += 256)
        atomicAdd(&h[dst[e] >> BSH], 1);
    __syncthreads();
    if (t < NB_C) hist[(size_t)t * nch + c] = h[t];
}

// ---- pass A2: exclusive scan of each bucket row (in place), total -> btotal ----
__global__ void scanb_kernel(int* __restrict__ hist, int* __restrict__ btotal, int nch) {
    __shared__ int s[256];
    const int b = blockIdx.x, t = threadIdx.x;
    int* row = hist + (size_t)b * nch;
    const int K = (nch + 255) / 256;
    int loc[8]; int tot = 0;
    for (int i = 0; i < K; ++i) {
        int idx = t * K + i;
        int v = (idx < nch) ? row[idx] : 0;
        loc[i] = tot; tot += v;
    }
    s[t] = tot; const int own = tot; __syncthreads();
    for (int off = 1; off < 256; off <<= 1) {
        int a = (t >= off) ? s[t - off] : 0; __syncthreads();
        s[t] += a; __syncthreads();
    }
    const int excl = s[t] - own;
    for (int i = 0; i < K; ++i) {
        int idx = t * K + i;
        if (idx < nch) row[idx] = excl + loc[i];
    }
    if (t == 255) btotal[b] = s[255];
}

// ---- pass A3: exclusive scan of bucket totals -> colbase[NB_C+1] ----
__global__ void scanc_kernel(const int* __restrict__ btotal, int* __restrict__ colbase, int NB_C) {
    __shared__ int s[256];
    const int t = threadIdx.x;
    int v = (t < NB_C) ? btotal[t] : 0;
    s[t] = v; const int own = v; __syncthreads();
    for (int off = 1; off < 256; off <<= 1) {
        int a = (t >= off) ? s[t - off] : 0; __syncthreads();
        s[t] += a; __syncthreads();
    }
    if (t < NB_C) colbase[t] = s[t] - own;
    if (t == 255) colbase[NB_C] = s[255];
}

// ---- pass A4: scatter (dst,src) pairs to exact slots; LDS cursors only ----
__global__ void scat_kernel(const int* __restrict__ src, const int* __restrict__ dst,
                            const int* __restrict__ hist, const int* __restrict__ colbase,
                            int2* __restrict__ pairs, int NB_C, int nch, int E) {
    __shared__ int cur[256];
    const int t = threadIdx.x, c = blockIdx.x;
    if (t < NB_C) cur[t] = colbase[t] + hist[(size_t)t * nch + c];
    __syncthreads();
    const int e0 = c * CH, e1 = min(e0 + CH, E);
    for (int e = e0 + t; e < e1; e += 256) {
        int d = dst[e];
        int b = d >> BSH;
        int p = atomicAdd(&cur[b], 1);
        pairs[p] = make_int2(d, src[e]);
    }
}

// ---- pass B: per-bucket CSR build (block = 1024-node bucket) ----
__global__ __launch_bounds__(256) void csrb_kernel(const int2* __restrict__ pairs,
                                                   const int* __restrict__ colbase,
                                                   int* __restrict__ cnt, int* __restrict__ rowptr,
                                                   float* __restrict__ dinv, int* __restrict__ list,
                                                   int N) {
    __shared__ int deg[BN];
    __shared__ int lex[BN];
    __shared__ int s[256];
    const int b = blockIdx.x, t = threadIdx.x;
    const int n0 = b << BSH;
    const int g0 = colbase[b], g1 = colbase[b + 1];
    for (int i = t; i < BN; i += 256) deg[i] = 0;
    __syncthreads();
    for (int i = g0 + t; i < g1; i += 256)
        atomicAdd(&deg[pairs[i].x - n0], 1);
    __syncthreads();
    const int b4 = t * 4;
    const int l0 = deg[b4], l1 = deg[b4 + 1], l2 = deg[b4 + 2], l3 = deg[b4 + 3];
    const int tot = l0 + l1 + l2 + l3;
    s[t] = tot; const int own = tot; __syncthreads();
    for (int off = 1; off < 256; off <<= 1) {
        int a = (t >= off) ? s[t - off] : 0; __syncthreads();
        s[t] += a; __syncthreads();
    }
    const int excl = s[t] - own;
    lex[b4] = excl; lex[b4 + 1] = excl + l0; lex[b4 + 2] = excl + l0 + l1; lex[b4 + 3] = excl + l0 + l1 + l2;
#pragma unroll
    for (int k = 0; k < 4; ++k) {
        int n = n0 + b4 + k;
        if (n < N) {
            int dg = deg[b4 + k];
            cnt[n] = dg;
            rowptr[n] = g0 + lex[b4 + k];
            dinv[n] = rsqrtf((float)dg + 1.0f);
        }
    }
    __syncthreads();
    for (int i = t; i < BN; i += 256) deg[i] = 0;   // reuse as cursors
    __syncthreads();
    for (int i = g0 + t; i < g1; i += 256) {
        int2 pr = pairs[i];
        int ld = pr.x - n0;
        int p = lex[ld] + atomicAdd(&deg[ld], 1);
        list[g0 + p] = pr.y;
    }
}

// ---------------- layer-1 GEMM: out = (x @ W) * dinv, K=256, D=32 ----------------
// BM=256 rows, 128 threads (2 waves). Thread (rg=t>>2, cg=t&3) owns rows
// {rg+32i} x cols cg*8..+7 (8x8 acc). BK=32: each row staged as one full
// 128B line (8 lanes/row). Register-dbuf: issue kc+1 loads before compute.
// LDS 45KB -> 3 blocks/CU; grid 782 = 3.05 blocks/CU.
__global__ __launch_bounds__(128) void linear1_kernel(const float* __restrict__ x,
                                                      const float* __restrict__ W,
                                                      const float* __restrict__ dinv,
                                                      float* __restrict__ out, int N) {
    __shared__ float xs[256][40];      // 40 KB; reads: quads {0,8,16,24} + bcast
    __shared__ float Wk[32][40];       // 5 KB
    const int t = threadIdx.x;
    const int rg = t >> 2;             // 0..31
    const int cg = t & 3;              // 0..3  cols cg*8..+7
    const int f  = t & 7;              // staging: float4 slot within 128B row chunk
    const int sr = t >> 3;             // staging: 0..15, rows sr+16i
    const long row0 = (long)blockIdx.x * 256;

    float4 xst[16];
    float4 wst[2];
    float acc[8][8] = {};

    auto load_chunk = [&](int kc) {
#pragma unroll
        for (int i = 0; i < 16; ++i) {
            long r = row0 + sr + 16 * i;
            xst[i] = (r < N) ? *(const float4*)(x + r * F_IN + kc * 32 + f * 4)
                             : make_float4(0.f, 0.f, 0.f, 0.f);
        }
#pragma unroll
        for (int j = 0; j < 2; ++j)
            wst[j] = *(const float4*)(W + kc * 1024 + t * 8 + j * 4);
    };
    auto write_chunk = [&]() {
#pragma unroll
        for (int i = 0; i < 16; ++i)
            *(float4*)&xs[sr + 16 * i][f * 4] = xst[i];
#pragma unroll
        for (int j = 0; j < 2; ++j) {
            int w = t * 8 + j * 4;
            *(float4*)&Wk[w >> 5][w & 31] = wst[j];
        }
    };

    load_chunk(0);
    write_chunk();
    __syncthreads();

    for (int kc = 0; kc < 8; ++kc) {
        if (kc < 7) load_chunk(kc + 1);          // in flight during compute
#pragma unroll
        for (int k4 = 0; k4 < 8; ++k4) {
            float4 xr[8];
#pragma unroll
            for (int i = 0; i < 8; ++i) xr[i] = *(float4*)&xs[rg + 32 * i][k4 * 4];
#pragma unroll
            for (int j = 0; j < 4; ++j) {
                const int kk = k4 * 4 + j;
                const float4 w0 = *(float4*)&Wk[kk][cg * 8];
                const float4 w1 = *(float4*)&Wk[kk][cg * 8 + 4];
#pragma unroll
                for (int i = 0; i < 8; ++i) {
                    const float xv = (j == 0) ? xr[i].x : (j == 1) ? xr[i].y
                                   : (j == 2) ? xr[i].z : xr[i].w;
                    acc[i][0] += xv * w0.x; acc[i][1] += xv * w0.y;
                    acc[i][2] += xv * w0.z; acc[i][3] += xv * w0.w;
                    acc[i][4] += xv * w1.x; acc[i][5] += xv * w1.y;
                    acc[i][6] += xv * w1.z; acc[i][7] += xv * w1.w;
                }
            }
        }
        __syncthreads();                          // all waves done reading xs/Wk
        if (kc < 7) {
            write_chunk();                        // vmcnt wait folded here
            __syncthreads();                      // new chunk visible
        }
    }
#pragma unroll
    for (int i = 0; i < 8; ++i) {
        long r = row0 + rg + 32 * i;
        if (r >= N) continue;
        float dv = dinv[r];
        float4 o0 = make_float4(acc[i][0] * dv, acc[i][1] * dv, acc[i][2] * dv, acc[i][3] * dv);
        float4 o1 = make_float4(acc[i][4] * dv, acc[i][5] * dv, acc[i][6] * dv, acc[i][7] * dv);
        *(float4*)(out + r * 32 + cg * 8) = o0;
        *(float4*)(out + r * 32 + cg * 8 + 4) = o1;
    }
}

// ---------------- small linear: out = (x @ W) * dinv, thread per row ----------------
template <int K, int D>
__global__ void linear_small_kernel(const float* __restrict__ x, const float* __restrict__ W,
                                    const float* __restrict__ dinv, float* __restrict__ out, int N) {
    __shared__ float Ws[K * D];
    const int t = threadIdx.x;
    for (int i = t; i < K * D; i += 256) Ws[i] = W[i];
    __syncthreads();
    long row = (long)blockIdx.x * 256 + t;
    if (row >= N) return;
    float acc[D] = {};
    const float4* xr = (const float4*)(x + row * K);
#pragma unroll
    for (int k4 = 0; k4 < K / 4; ++k4) {
        float4 xv = xr[k4];
        float xvs[4] = {xv.x, xv.y, xv.z, xv.w};
#pragma unroll
        for (int j = 0; j < 4; ++j) {
#pragma unroll
            for (int c4 = 0; c4 < D / 4; ++c4) {
                float4 w = *(const float4*)&Ws[(k4 * 4 + j) * D + c4 * 4];
                acc[c4 * 4 + 0] += xvs[j] * w.x;
                acc[c4 * 4 + 1] += xvs[j] * w.y;
                acc[c4 * 4 + 2] += xvs[j] * w.z;
                acc[c4 * 4 + 3] += xvs[j] * w.w;
            }
        }
    }
    float dv = dinv[row];
#pragma unroll
    for (int c4 = 0; c4 < D / 4; ++c4) {
        float4 o = make_float4(acc[c4 * 4 + 0] * dv, acc[c4 * 4 + 1] * dv,
                               acc[c4 * 4 + 2] * dv, acc[c4 * 4 + 3] * dv);
        *(float4*)(out + row * D + c4 * 4) = o;
    }
}

// ---------------- gather: out_i = tanh(dinv_i*(hs_i + sum hs_src) + b) ----------------
template <int D>
__global__ void gather_kernel(const int* __restrict__ rowptr, const int* __restrict__ cnt,
                              const int* __restrict__ list, const float* __restrict__ hs,
                              const float* __restrict__ dinv, const float* __restrict__ b,
                              float* __restrict__ out, int N) {
    constexpr int L = D / 4;
    constexpr int GPB = 256 / L;
    const int t = threadIdx.x;
    const int g = t / L, lane = t % L;
    long node = (long)blockIdx.x * GPB + g;
    if (node >= N) return;
    const int start = rowptr[node];
    const int num = cnt[node];
    const int* __restrict__ lp = list + start;
    const float4* __restrict__ hs4 = (const float4*)hs;
    float4 acc = hs4[node * L + lane];
    int j = 0;
    for (; j + 8 <= num; j += 8) {
        int s0 = lp[j], s1 = lp[j + 1], s2 = lp[j + 2], s3 = lp[j + 3];
        int s4 = lp[j + 4], s5 = lp[j + 5], s6 = lp[j + 6], s7 = lp[j + 7];
        float4 v0 = hs4[(long)s0 * L + lane], v1 = hs4[(long)s1 * L + lane];
        float4 v2 = hs4[(long)s2 * L + lane], v3 = hs4[(long)s3 * L + lane];
        float4 v4 = hs4[(long)s4 * L + lane], v5 = hs4[(long)s5 * L + lane];
        float4 v6 = hs4[(long)s6 * L + lane], v7 = hs4[(long)s7 * L + lane];
        acc.x += ((v0.x + v1.x) + (v2.x + v3.x)) + ((v4.x + v5.x) + (v6.x + v7.x));
        acc.y += ((v0.y + v1.y) + (v2.y + v3.y)) + ((v4.y + v5.y) + (v6.y + v7.y));
        acc.z += ((v0.z + v1.z) + (v2.z + v3.z)) + ((v4.z + v5.z) + (v6.z + v7.z));
        acc.w += ((v0.w + v1.w) + (v2.w + v3.w)) + ((v4.w + v5.w) + (v6.w + v7.w));
    }
    for (; j < num; ++j) {
        int s = lp[j];
        float4 v = hs4[(long)s * L + lane];
        acc.x += v.x; acc.y += v.y; acc.z += v.z; acc.w += v.w;
    }
    const float dv = dinv[node];
    const float4 bb = *(const float4*)(b + lane * 4);
    float4 o;
    o.x = tanhf(acc.x * dv + bb.x);
    o.y = tanhf(acc.y * dv + bb.y);
    o.z = tanhf(acc.z * dv + bb.z);
    o.w = tanhf(acc.w * dv + bb.w);
    *(float4*)(out + node * D + lane * 4) = o;
}

// ---------------- D=8 gather fused with classifier ----------------
__global__ void gather8_final_kernel(const int* __restrict__ rowptr, const int* __restrict__ cnt,
                                     const int* __restrict__ list, const float* __restrict__ hs,
                                     const float* __restrict__ dinv, const float* __restrict__ b,
                                     const float* __restrict__ Wc, const float* __restrict__ bc,
                                     float* __restrict__ out, int N) {
    const int t = threadIdx.x;
    const int g = t >> 1, lane = t & 1;
    long node = (long)blockIdx.x * 128 + g;
    if (node >= N) return;
    const int start = rowptr[node];
    const int num = cnt[node];
    const int* __restrict__ lp = list + start;
    const float4* __restrict__ hs4 = (const float4*)hs;
    float4 acc = hs4[node * 2 + lane];
    int j = 0;
    for (; j + 8 <= num; j += 8) {
        int s0 = lp[j], s1 = lp[j + 1], s2 = lp[j + 2], s3 = lp[j + 3];
        int s4 = lp[j + 4], s5 = lp[j + 5], s6 = lp[j + 6], s7 = lp[j + 7];
        float4 v0 = hs4[(long)s0 * 2 + lane], v1 = hs4[(long)s1 * 2 + lane];
        float4 v2 = hs4[(long)s2 * 2 + lane], v3 = hs4[(long)s3 * 2 + lane];
        float4 v4 = hs4[(long)s4 * 2 + lane], v5 = hs4[(long)s5 * 2 + lane];
        float4 v6 = hs4[(long)s6 * 2 + lane], v7 = hs4[(long)s7 * 2 + lane];
        acc.x += ((v0.x + v1.x) + (v2.x + v3.x)) + ((v4.x + v5.x) + (v6.x + v7.x));
        acc.y += ((v0.y + v1.y) + (v2.y + v3.y)) + ((v4.y + v5.y) + (v6.y + v7.y));
        acc.z += ((v0.z + v1.z) + (v2.z + v3.z)) + ((v4.z + v5.z) + (v6.z + v7.z));
        acc.w += ((v0.w + v1.w) + (v2.w + v3.w)) + ((v4.w + v5.w) + (v6.w + v7.w));
    }
    for (; j < num; ++j) {
        int s = lp[j];
        float4 v = hs4[(long)s * 2 + lane];
        acc.x += v.x; acc.y += v.y; acc.z += v.z; acc.w += v.w;
    }
    const float dv = dinv[node];
    const float4 bb = *(const float4*)(b + lane * 4);
    float4 h;
    h.x = tanhf(acc.x * dv + bb.x);
    h.y = tanhf(acc.y * dv + bb.y);
    h.z = tanhf(acc.z * dv + bb.z);
    h.w = tanhf(acc.w * dv + bb.w);
    const float4 w0 = *(const float4*)(Wc + (lane * 4 + 0) * 4);
    const float4 w1 = *(const float4*)(Wc + (lane * 4 + 1) * 4);
    const float4 w2 = *(const float4*)(Wc + (lane * 4 + 2) * 4);
    const float4 w3 = *(const float4*)(Wc + (lane * 4 + 3) * 4);
    float4 p;
    p.x = h.x * w0.x + h.y * w1.x + h.z * w2.x + h.w * w3.x;
    p.y = h.x * w0.y + h.y * w1.y + h.z * w2.y + h.w * w3.y;
    p.z = h.x * w0.z + h.y * w1.z + h.z * w2.z + h.w * w3.z;
    p.w = h.x * w0.w + h.y * w1.w + h.z * w2.w + h.w * w3.w;
    p.x += __shfl_xor(p.x, 1);
    p.y += __shfl_xor(p.y, 1);
    p.z += __shfl_xor(p.z, 1);
    p.w += __shfl_xor(p.w, 1);
    if (lane == 0) {
        const float4 bcv = *(const float4*)bc;
        float4 o = make_float4(p.x + bcv.x, p.y + bcv.y, p.z + bcv.z, p.w + bcv.w);
        *(float4*)(out + node * 4) = o;
    }
}

extern "C" void kernel_launch(void* const* d_in, const int* in_sizes, int n_in,
                              void* d_out, int out_size, void* d_ws, size_t ws_size,
                              hipStream_t stream) {
    const float* x  = (const float*)d_in[0];
    const int*   ei = (const int*)d_in[1];
    const float* W1 = (const float*)d_in[2];
    const float* b1 = (const float*)d_in[3];
    const float* W2 = (const float*)d_in[4];
    const float* b2 = (const float*)d_in[5];
    const float* W3 = (const float*)d_in[6];
    const float* b3 = (const float*)d_in[7];
    const float* Wc = (const float*)d_in[8];
    const float* bc = (const float*)d_in[9];
    float* out = (float*)d_out;

    const int N = in_sizes[0] / F_IN;
    const int E = in_sizes[1] / 2;
    const int* src = ei;
    const int* dst = ei + E;
    const int B = 256;

    const int NB_C = (N + BN - 1) >> BSH;       // coarse buckets (196) <= 256
    const int nch  = (E + CH - 1) / CH;         // chunks (391)

    char* p = (char*)d_ws;
    auto take = [&](size_t bytes) { char* q = p; p += (bytes + 255) & ~size_t(255); return q; };
    int*   cnt     = (int*)take((size_t)N * 4);
    int*   rowptr  = (int*)take((size_t)N * 4);
    float* dinv    = (float*)take((size_t)N * 4);
    int*   hist    = (int*)take((size_t)NB_C * nch * 4);
    int*   btotal  = (int*)take((size_t)NB_C * 4);
    int*   colbase = (int*)take((size_t)(NB_C + 1) * 4);
    int*   list    = (int*)take((size_t)E * 4);
    float* bufA    = (float*)take((size_t)N * 32 * 4);
    float* bufB    = (float*)take((size_t)N * 32 * 4);
    int2*  pairs   = (int2*)bufA;   // alias: pairs dead before linear1 writes bufA

    // ---- CSR build (deterministic two-level counting sort) ----
    histc_kernel<<<nch, B, 0, stream>>>(dst, hist, NB_C, nch, E);
    scanb_kernel<<<NB_C, B, 0, stream>>>(hist, btotal, nch);
    scanc_kernel<<<1, B, 0, stream>>>(btotal, colbase, NB_C);
    scat_kernel<<<nch, B, 0, stream>>>(src, dst, hist, colbase, pairs, NB_C, nch, E);
    csrb_kernel<<<NB_C, B, 0, stream>>>(pairs, colbase, cnt, rowptr, dinv, list, N);

    // ---- layer 1: 256 -> 32 ----
    linear1_kernel<<<(N + 255) / 256, 128, 0, stream>>>(x, W1, dinv, bufA, N);
    gather_kernel<32><<<(N + 31) / 32, B, 0, stream>>>(rowptr, cnt, list, bufA, dinv, b1, bufB, N);
    // ---- layer 2: 32 -> 16 ----
    linear_small_kernel<32, 16><<<(N + 255) / 256, B, 0, stream>>>(bufB, W2, dinv, bufA, N);
    gather_kernel<16><<<(N + 63) / 64, B, 0, stream>>>(rowptr, cnt, list, bufA, dinv, b2, bufB, N);
    // ---- layer 3: 16 -> 8, classifier fused ----
    linear_small_kernel<16, 8><<<(N + 255) / 256, B, 0, stream>>>(bufB, W3, dinv, bufA, N);
    gather8_final_kernel<<<(N + 127) / 128, B, 0, stream>>>(rowptr, cnt, list, bufA, dinv, b3, Wc, bc, out, N);
}

// Round 8
// 401.538 us; speedup vs baseline: 1.6852x; 1.6852x over previous
//
#include <hip/hip_runtime.h>

// GCN: 3x (linear -> symmetric-norm conv -> bias -> tanh) -> linear.
// N=200000, E=3200000, F=256->32->16->8->4, fp32.
// Round 8: linear1 v4 — revert round-7 reg-dbuf (spilled @256 VGPR).
// BM=256, 256 threads, 4x8 thread tile (32 out/thread => 37% occ ceiling),
// BK=32 full-line staging, pitch-36 aligned LDS (b128, conflict-audited),
// per-chunk W staging, 41KB LDS => 3 blocks/CU, grid 782. Rest = round 5.
// Algebra: norm = dinv[s]*dinv[d]  =>  agg_i = dinv_i * (hs_i + sum_in hs_src)
// with hs = (h @ W) * dinv computed in each linear's epilogue.

constexpr int F_IN = 256;
constexpr int BSH = 10;            // nodes per coarse bucket = 1024
constexpr int BN  = 1 << BSH;
constexpr int CH  = 8192;          // edges per chunk

// ---- pass A1: per-chunk bucket histogram (transposed store: hist[b][c]) ----
__global__ void histc_kernel(const int* __restrict__ dst, int* __restrict__ hist,
                             int NB_C, int nch, int E) {
    __shared__ int h[256];
    const int t = threadIdx.x, c = blockIdx.x;
    h[t] = 0; __syncthreads();
    const int e0 = c * CH, e1 = min(e0 + CH, E);
    for (int e = e0 + t; e < e1; e += 256)
        atomicAdd(&h[dst[e] >> BSH], 1);
    __syncthreads();
    if (t < NB_C) hist[(size_t)t * nch + c] = h[t];
}

// ---- pass A2: exclusive scan of each bucket row (in place), total -> btotal ----
__global__ void scanb_kernel(int* __restrict__ hist, int* __restrict__ btotal, int nch) {
    __shared__ int s[256];
    const int b = blockIdx.x, t = threadIdx.x;
    int* row = hist + (size_t)b * nch;
    const int K = (nch + 255) / 256;
    int loc[8]; int tot = 0;
    for (int i = 0; i < K; ++i) {
        int idx = t * K + i;
        int v = (idx < nch) ? row[idx] : 0;
        loc[i] = tot; tot += v;
    }
    s[t] = tot; const int own = tot; __syncthreads();
    for (int off = 1; off < 256; off <<= 1) {
        int a = (t >= off) ? s[t - off] : 0; __syncthreads();
        s[t] += a; __syncthreads();
    }
    const int excl = s[t] - own;
    for (int i = 0; i < K; ++i) {
        int idx = t * K + i;
        if (idx < nch) row[idx] = excl + loc[i];
    }
    if (t == 255) btotal[b] = s[255];
}

// ---- pass A3: exclusive scan of bucket totals -> colbase[NB_C+1] ----
__global__ void scanc_kernel(const int* __restrict__ btotal, int* __restrict__ colbase, int NB_C) {
    __shared__ int s[256];
    const int t = threadIdx.x;
    int v = (t < NB_C) ? btotal[t] : 0;
    s[t] = v; const int own = v; __syncthreads();
    for (int off = 1; off < 256; off <<= 1) {
        int a = (t >= off) ? s[t - off] : 0; __syncthreads();
        s[t] += a; __syncthreads();
    }
    if (t < NB_C) colbase[t] = s[t] - own;
    if (t == 255) colbase[NB_C] = s[255];
}

// ---- pass A4: scatter (dst,src) pairs to exact slots; LDS cursors only ----
__global__ void scat_kernel(const int* __restrict__ src, const int* __restrict__ dst,
                            const int* __restrict__ hist, const int* __restrict__ colbase,
                            int2* __restrict__ pairs, int NB_C, int nch, int E) {
    __shared__ int cur[256];
    const int t = threadIdx.x, c = blockIdx.x;
    if (t < NB_C) cur[t] = colbase[t] + hist[(size_t)t * nch + c];
    __syncthreads();
    const int e0 = c * CH, e1 = min(e0 + CH, E);
    for (int e = e0 + t; e < e1; e += 256) {
        int d = dst[e];
        int b = d >> BSH;
        int p = atomicAdd(&cur[b], 1);
        pairs[p] = make_int2(d, src[e]);
    }
}

// ---- pass B: per-bucket CSR build (block = 1024-node bucket) ----
__global__ __launch_bounds__(256) void csrb_kernel(const int2* __restrict__ pairs,
                                                   const int* __restrict__ colbase,
                                                   int* __restrict__ cnt, int* __restrict__ rowptr,
                                                   float* __restrict__ dinv, int* __restrict__ list,
                                                   int N) {
    __shared__ int deg[BN];
    __shared__ int lex[BN];
    __shared__ int s[256];
    const int b = blockIdx.x, t = threadIdx.x;
    const int n0 = b << BSH;
    const int g0 = colbase[b], g1 = colbase[b + 1];
    for (int i = t; i < BN; i += 256) deg[i] = 0;
    __syncthreads();
    for (int i = g0 + t; i < g1; i += 256)
        atomicAdd(&deg[pairs[i].x - n0], 1);
    __syncthreads();
    const int b4 = t * 4;
    const int l0 = deg[b4], l1 = deg[b4 + 1], l2 = deg[b4 + 2], l3 = deg[b4 + 3];
    const int tot = l0 + l1 + l2 + l3;
    s[t] = tot; const int own = tot; __syncthreads();
    for (int off = 1; off < 256; off <<= 1) {
        int a = (t >= off) ? s[t - off] : 0; __syncthreads();
        s[t] += a; __syncthreads();
    }
    const int excl = s[t] - own;
    lex[b4] = excl; lex[b4 + 1] = excl + l0; lex[b4 + 2] = excl + l0 + l1; lex[b4 + 3] = excl + l0 + l1 + l2;
#pragma unroll
    for (int k = 0; k < 4; ++k) {
        int n = n0 + b4 + k;
        if (n < N) {
            int dg = deg[b4 + k];
            cnt[n] = dg;
            rowptr[n] = g0 + lex[b4 + k];
            dinv[n] = rsqrtf((float)dg + 1.0f);
        }
    }
    __syncthreads();
    for (int i = t; i < BN; i += 256) deg[i] = 0;   // reuse as cursors
    __syncthreads();
    for (int i = g0 + t; i < g1; i += 256) {
        int2 pr = pairs[i];
        int ld = pr.x - n0;
        int p = lex[ld] + atomicAdd(&deg[ld], 1);
        list[g0 + p] = pr.y;
    }
}

// ---------------- layer-1 GEMM: out = (x @ W) * dinv, K=256, D=32 ----------------
// BM=256 rows, 256 threads. Thread (rg=t>>2 in 0..63, cg=t&3) owns rows
// {rg+64i, i<4} x cols cg*8..+7 (4x8 acc = 32 out/thread, 37% occ ceiling).
// BK=32: each row staged as one 128B line by 8 lanes. Pitch 36 floats:
// 16B-aligned b128; x-reads hit 4 distinct banks (rows differ by 36*4B),
// W-reads broadcast per 4-lane quad; staging worst-case 2-way (free).
// LDS 41KB -> 3 blocks/CU; grid 782 = 3.05 blocks/CU. No reg pipelining.
__global__ __launch_bounds__(256) void linear1_kernel(const float* __restrict__ x,
                                                      const float* __restrict__ W,
                                                      const float* __restrict__ dinv,
                                                      float* __restrict__ out, int N) {
    __shared__ float xs[256][36];      // 36 KB
    __shared__ float Wk[32][36];       // 4.5 KB
    const int t = threadIdx.x;
    const int rg = t >> 2;             // 0..63
    const int cg = t & 3;              // cols cg*8..+7
    const int f  = t & 7;              // staging float4 slot in 128B row chunk
    const int sr = t >> 3;             // staging rows sr+32i
    const long row0 = (long)blockIdx.x * 256;
    float acc[4][8] = {};

    for (int kc = 0; kc < 8; ++kc) {
        // stage W chunk [32k x 32c]: one float4 per thread, contiguous global
        {
            const int wr = t >> 3, wc = (t & 7) * 4;
            *(float4*)&Wk[wr][wc] = *(const float4*)(W + (kc * 32 + wr) * 32 + wc);
        }
        // stage x tile: 8 rows per thread-pass, full 128B line per row
#pragma unroll
        for (int i = 0; i < 8; ++i) {
            const int r = sr + 32 * i;
            const long gr = row0 + r;
            float4 v = make_float4(0.f, 0.f, 0.f, 0.f);
            if (gr < N) v = *(const float4*)(x + gr * F_IN + kc * 32 + f * 4);
            *(float4*)&xs[r][f * 4] = v;
        }
        __syncthreads();
#pragma unroll
        for (int k4 = 0; k4 < 8; ++k4) {
            float4 xr[4];
#pragma unroll
            for (int i = 0; i < 4; ++i) xr[i] = *(float4*)&xs[rg + 64 * i][k4 * 4];
#pragma unroll
            for (int j = 0; j < 4; ++j) {
                const int kk = k4 * 4 + j;
                const float4 w0 = *(float4*)&Wk[kk][cg * 8];
                const float4 w1 = *(float4*)&Wk[kk][cg * 8 + 4];
#pragma unroll
                for (int i = 0; i < 4; ++i) {
                    const float xv = (j == 0) ? xr[i].x : (j == 1) ? xr[i].y
                                   : (j == 2) ? xr[i].z : xr[i].w;
                    acc[i][0] += xv * w0.x; acc[i][1] += xv * w0.y;
                    acc[i][2] += xv * w0.z; acc[i][3] += xv * w0.w;
                    acc[i][4] += xv * w1.x; acc[i][5] += xv * w1.y;
                    acc[i][6] += xv * w1.z; acc[i][7] += xv * w1.w;
                }
            }
        }
        __syncthreads();
    }
#pragma unroll
    for (int i = 0; i < 4; ++i) {
        const long r = row0 + rg + 64 * i;
        if (r >= N) continue;
        const float dv = dinv[r];
        float4 o0 = make_float4(acc[i][0] * dv, acc[i][1] * dv, acc[i][2] * dv, acc[i][3] * dv);
        float4 o1 = make_float4(acc[i][4] * dv, acc[i][5] * dv, acc[i][6] * dv, acc[i][7] * dv);
        *(float4*)(out + r * 32 + cg * 8) = o0;
        *(float4*)(out + r * 32 + cg * 8 + 4) = o1;
    }
}

// ---------------- small linear: out = (x @ W) * dinv, thread per row ----------------
template <int K, int D>
__global__ void linear_small_kernel(const float* __restrict__ x, const float* __restrict__ W,
                                    const float* __restrict__ dinv, float* __restrict__ out, int N) {
    __shared__ float Ws[K * D];
    const int t = threadIdx.x;
    for (int i = t; i < K * D; i += 256) Ws[i] = W[i];
    __syncthreads();
    long row = (long)blockIdx.x * 256 + t;
    if (row >= N) return;
    float acc[D] = {};
    const float4* xr = (const float4*)(x + row * K);
#pragma unroll
    for (int k4 = 0; k4 < K / 4; ++k4) {
        float4 xv = xr[k4];
        float xvs[4] = {xv.x, xv.y, xv.z, xv.w};
#pragma unroll
        for (int j = 0; j < 4; ++j) {
#pragma unroll
            for (int c4 = 0; c4 < D / 4; ++c4) {
                float4 w = *(const float4*)&Ws[(k4 * 4 + j) * D + c4 * 4];
                acc[c4 * 4 + 0] += xvs[j] * w.x;
                acc[c4 * 4 + 1] += xvs[j] * w.y;
                acc[c4 * 4 + 2] += xvs[j] * w.z;
                acc[c4 * 4 + 3] += xvs[j] * w.w;
            }
        }
    }
    float dv = dinv[row];
#pragma unroll
    for (int c4 = 0; c4 < D / 4; ++c4) {
        float4 o = make_float4(acc[c4 * 4 + 0] * dv, acc[c4 * 4 + 1] * dv,
                               acc[c4 * 4 + 2] * dv, acc[c4 * 4 + 3] * dv);
        *(float4*)(out + row * D + c4 * 4) = o;
    }
}

// ---------------- gather: out_i = tanh(dinv_i*(hs_i + sum hs_src) + b) ----------------
template <int D>
__global__ void gather_kernel(const int* __restrict__ rowptr, const int* __restrict__ cnt,
                              const int* __restrict__ list, const float* __restrict__ hs,
                              const float* __restrict__ dinv, const float* __restrict__ b,
                              float* __restrict__ out, int N) {
    constexpr int L = D / 4;
    constexpr int GPB = 256 / L;
    const int t = threadIdx.x;
    const int g = t / L, lane = t % L;
    long node = (long)blockIdx.x * GPB + g;
    if (node >= N) return;
    const int start = rowptr[node];
    const int num = cnt[node];
    const int* __restrict__ lp = list + start;
    const float4* __restrict__ hs4 = (const float4*)hs;
    float4 acc = hs4[node * L + lane];
    int j = 0;
    for (; j + 8 <= num; j += 8) {
        int s0 = lp[j], s1 = lp[j + 1], s2 = lp[j + 2], s3 = lp[j + 3];
        int s4 = lp[j + 4], s5 = lp[j + 5], s6 = lp[j + 6], s7 = lp[j + 7];
        float4 v0 = hs4[(long)s0 * L + lane], v1 = hs4[(long)s1 * L + lane];
        float4 v2 = hs4[(long)s2 * L + lane], v3 = hs4[(long)s3 * L + lane];
        float4 v4 = hs4[(long)s4 * L + lane], v5 = hs4[(long)s5 * L + lane];
        float4 v6 = hs4[(long)s6 * L + lane], v7 = hs4[(long)s7 * L + lane];
        acc.x += ((v0.x + v1.x) + (v2.x + v3.x)) + ((v4.x + v5.x) + (v6.x + v7.x));
        acc.y += ((v0.y + v1.y) + (v2.y + v3.y)) + ((v4.y + v5.y) + (v6.y + v7.y));
        acc.z += ((v0.z + v1.z) + (v2.z + v3.z)) + ((v4.z + v5.z) + (v6.z + v7.z));
        acc.w += ((v0.w + v1.w) + (v2.w + v3.w)) + ((v4.w + v5.w) + (v6.w + v7.w));
    }
    for (; j < num; ++j) {
        int s = lp[j];
        float4 v = hs4[(long)s * L + lane];
        acc.x += v.x; acc.y += v.y; acc.z += v.z; acc.w += v.w;
    }
    const float dv = dinv[node];
    const float4 bb = *(const float4*)(b + lane * 4);
    float4 o;
    o.x = tanhf(acc.x * dv + bb.x);
    o.y = tanhf(acc.y * dv + bb.y);
    o.z = tanhf(acc.z * dv + bb.z);
    o.w = tanhf(acc.w * dv + bb.w);
    *(float4*)(out + node * D + lane * 4) = o;
}

// ---------------- D=8 gather fused with classifier ----------------
__global__ void gather8_final_kernel(const int* __restrict__ rowptr, const int* __restrict__ cnt,
                                     const int* __restrict__ list, const float* __restrict__ hs,
                                     const float* __restrict__ dinv, const float* __restrict__ b,
                                     const float* __restrict__ Wc, const float* __restrict__ bc,
                                     float* __restrict__ out, int N) {
    const int t = threadIdx.x;
    const int g = t >> 1, lane = t & 1;
    long node = (long)blockIdx.x * 128 + g;
    if (node >= N) return;
    const int start = rowptr[node];
    const int num = cnt[node];
    const int* __restrict__ lp = list + start;
    const float4* __restrict__ hs4 = (const float4*)hs;
    float4 acc = hs4[node * 2 + lane];
    int j = 0;
    for (; j + 8 <= num; j += 8) {
        int s0 = lp[j], s1 = lp[j + 1], s2 = lp[j + 2], s3 = lp[j + 3];
        int s4 = lp[j + 4], s5 = lp[j + 5], s6 = lp[j + 6], s7 = lp[j + 7];
        float4 v0 = hs4[(long)s0 * 2 + lane], v1 = hs4[(long)s1 * 2 + lane];
        float4 v2 = hs4[(long)s2 * 2 + lane], v3 = hs4[(long)s3 * 2 + lane];
        float4 v4 = hs4[(long)s4 * 2 + lane], v5 = hs4[(long)s5 * 2 + lane];
        float4 v6 = hs4[(long)s6 * 2 + lane], v7 = hs4[(long)s7 * 2 + lane];
        acc.x += ((v0.x + v1.x) + (v2.x + v3.x)) + ((v4.x + v5.x) + (v6.x + v7.x));
        acc.y += ((v0.y + v1.y) + (v2.y + v3.y)) + ((v4.y + v5.y) + (v6.y + v7.y));
        acc.z += ((v0.z + v1.z) + (v2.z + v3.z)) + ((v4.z + v5.z) + (v6.z + v7.z));
        acc.w += ((v0.w + v1.w) + (v2.w + v3.w)) + ((v4.w + v5.w) + (v6.w + v7.w));
    }
    for (; j < num; ++j) {
        int s = lp[j];
        float4 v = hs4[(long)s * 2 + lane];
        acc.x += v.x; acc.y += v.y; acc.z += v.z; acc.w += v.w;
    }
    const float dv = dinv[node];
    const float4 bb = *(const float4*)(b + lane * 4);
    float4 h;
    h.x = tanhf(acc.x * dv + bb.x);
    h.y = tanhf(acc.y * dv + bb.y);
    h.z = tanhf(acc.z * dv + bb.z);
    h.w = tanhf(acc.w * dv + bb.w);
    const float4 w0 = *(const float4*)(Wc + (lane * 4 + 0) * 4);
    const float4 w1 = *(const float4*)(Wc + (lane * 4 + 1) * 4);
    const float4 w2 = *(const float4*)(Wc + (lane * 4 + 2) * 4);
    const float4 w3 = *(const float4*)(Wc + (lane * 4 + 3) * 4);
    float4 p;
    p.x = h.x * w0.x + h.y * w1.x + h.z * w2.x + h.w * w3.x;
    p.y = h.x * w0.y + h.y * w1.y + h.z * w2.y + h.w * w3.y;
    p.z = h.x * w0.z + h.y * w1.z + h.z * w2.z + h.w * w3.z;
    p.w = h.x * w0.w + h.y * w1.w + h.z * w2.w + h.w * w3.w;
    p.x += __shfl_xor(p.x, 1);
    p.y += __shfl_xor(p.y, 1);
    p.z += __shfl_xor(p.z, 1);
    p.w += __shfl_xor(p.w, 1);
    if (lane == 0) {
        const float4 bcv = *(const float4*)bc;
        float4 o = make_float4(p.x + bcv.x, p.y + bcv.y, p.z + bcv.z, p.w + bcv.w);
        *(float4*)(out + node * 4) = o;
    }
}

extern "C" void kernel_launch(void* const* d_in, const int* in_sizes, int n_in,
                              void* d_out, int out_size, void* d_ws, size_t ws_size,
                              hipStream_t stream) {
    const float* x  = (const float*)d_in[0];
    const int*   ei = (const int*)d_in[1];
    const float* W1 = (const float*)d_in[2];
    const float* b1 = (const float*)d_in[3];
    const float* W2 = (const float*)d_in[4];
    const float* b2 = (const float*)d_in[5];
    const float* W3 = (const float*)d_in[6];
    const float* b3 = (const float*)d_in[7];
    const float* Wc = (const float*)d_in[8];
    const float* bc = (const float*)d_in[9];
    float* out = (float*)d_out;

    const int N = in_sizes[0] / F_IN;
    const int E = in_sizes[1] / 2;
    const int* src = ei;
    const int* dst = ei + E;
    const int B = 256;

    const int NB_C = (N + BN - 1) >> BSH;       // coarse buckets (196) <= 256
    const int nch  = (E + CH - 1) / CH;         // chunks (391)

    char* p = (char*)d_ws;
    auto take = [&](size_t bytes) { char* q = p; p += (bytes + 255) & ~size_t(255); return q; };
    int*   cnt     = (int*)take((size_t)N * 4);
    int*   rowptr  = (int*)take((size_t)N * 4);
    float* dinv    = (float*)take((size_t)N * 4);
    int*   hist    = (int*)take((size_t)NB_C * nch * 4);
    int*   btotal  = (int*)take((size_t)NB_C * 4);
    int*   colbase = (int*)take((size_t)(NB_C + 1) * 4);
    int*   list    = (int*)take((size_t)E * 4);
    float* bufA    = (float*)take((size_t)N * 32 * 4);
    float* bufB    = (float*)take((size_t)N * 32 * 4);
    int2*  pairs   = (int2*)bufA;   // alias: pairs dead before linear1 writes bufA

    // ---- CSR build (deterministic two-level counting sort) ----
    histc_kernel<<<nch, B, 0, stream>>>(dst, hist, NB_C, nch, E);
    scanb_kernel<<<NB_C, B, 0, stream>>>(hist, btotal, nch);
    scanc_kernel<<<1, B, 0, stream>>>(btotal, colbase, NB_C);
    scat_kernel<<<nch, B, 0, stream>>>(src, dst, hist, colbase, pairs, NB_C, nch, E);
    csrb_kernel<<<NB_C, B, 0, stream>>>(pairs, colbase, cnt, rowptr, dinv, list, N);

    // ---- layer 1: 256 -> 32 ----
    linear1_kernel<<<(N + 255) / 256, B, 0, stream>>>(x, W1, dinv, bufA, N);
    gather_kernel<32><<<(N + 31) / 32, B, 0, stream>>>(rowptr, cnt, list, bufA, dinv, b1, bufB, N);
    // ---- layer 2: 32 -> 16 ----
    linear_small_kernel<32, 16><<<(N + 255) / 256, B, 0, stream>>>(bufB, W2, dinv, bufA, N);
    gather_kernel<16><<<(N + 63) / 64, B, 0, stream>>>(rowptr, cnt, list, bufA, dinv, b2, bufB, N);
    // ---- layer 3: 16 -> 8, classifier fused ----
    linear_small_kernel<16, 8><<<(N + 255) / 256, B, 0, stream>>>(bufB, W3, dinv, bufA, N);
    gather8_final_kernel<<<(N + 127) / 128, B, 0, stream>>>(rowptr, cnt, list, bufA, dinv, b3, Wc, bc, out, N);
}

// Round 9
// 357.135 us; speedup vs baseline: 1.8948x; 1.1243x over previous
//
#include <hip/hip_runtime.h>

// GCN: 3x (linear -> symmetric-norm conv -> bias -> tanh) -> linear.
// N=200000, E=3200000, F=256->32->16->8->4, fp32.
// Round 9: linear1 v5 — single-barrier LDS double-buffer (T14 async split):
// per kc: issue next loads -> compute current buf -> write other buf -> 1 sync.
// BK=16 dbuf, 45KB LDS => 3 blocks/CU, ~20 staging VGPRs (no round-7 spill).
// Rest = round 5/8.
// Algebra: norm = dinv[s]*dinv[d]  =>  agg_i = dinv_i * (hs_i + sum_in hs_src)
// with hs = (h @ W) * dinv computed in each linear's epilogue.

constexpr int F_IN = 256;
constexpr int BSH = 10;            // nodes per coarse bucket = 1024
constexpr int BN  = 1 << BSH;
constexpr int CH  = 8192;          // edges per chunk

// ---- pass A1: per-chunk bucket histogram (transposed store: hist[b][c]) ----
__global__ void histc_kernel(const int* __restrict__ dst, int* __restrict__ hist,
                             int NB_C, int nch, int E) {
    __shared__ int h[256];
    const int t = threadIdx.x, c = blockIdx.x;
    h[t] = 0; __syncthreads();
    const int e0 = c * CH, e1 = min(e0 + CH, E);
    for (int e = e0 + t; e < e1; e += 256)
        atomicAdd(&h[dst[e] >> BSH], 1);
    __syncthreads();
    if (t < NB_C) hist[(size_t)t * nch + c] = h[t];
}

// ---- pass A2: exclusive scan of each bucket row (in place), total -> btotal ----
__global__ void scanb_kernel(int* __restrict__ hist, int* __restrict__ btotal, int nch) {
    __shared__ int s[256];
    const int b = blockIdx.x, t = threadIdx.x;
    int* row = hist + (size_t)b * nch;
    const int K = (nch + 255) / 256;
    int loc[8]; int tot = 0;
    for (int i = 0; i < K; ++i) {
        int idx = t * K + i;
        int v = (idx < nch) ? row[idx] : 0;
        loc[i] = tot; tot += v;
    }
    s[t] = tot; const int own = tot; __syncthreads();
    for (int off = 1; off < 256; off <<= 1) {
        int a = (t >= off) ? s[t - off] : 0; __syncthreads();
        s[t] += a; __syncthreads();
    }
    const int excl = s[t] - own;
    for (int i = 0; i < K; ++i) {
        int idx = t * K + i;
        if (idx < nch) row[idx] = excl + loc[i];
    }
    if (t == 255) btotal[b] = s[255];
}

// ---- pass A3: exclusive scan of bucket totals -> colbase[NB_C+1] ----
__global__ void scanc_kernel(const int* __restrict__ btotal, int* __restrict__ colbase, int NB_C) {
    __shared__ int s[256];
    const int t = threadIdx.x;
    int v = (t < NB_C) ? btotal[t] : 0;
    s[t] = v; const int own = v; __syncthreads();
    for (int off = 1; off < 256; off <<= 1) {
        int a = (t >= off) ? s[t - off] : 0; __syncthreads();
        s[t] += a; __syncthreads();
    }
    if (t < NB_C) colbase[t] = s[t] - own;
    if (t == 255) colbase[NB_C] = s[255];
}

// ---- pass A4: scatter (dst,src) pairs to exact slots; LDS cursors only ----
__global__ void scat_kernel(const int* __restrict__ src, const int* __restrict__ dst,
                            const int* __restrict__ hist, const int* __restrict__ colbase,
                            int2* __restrict__ pairs, int NB_C, int nch, int E) {
    __shared__ int cur[256];
    const int t = threadIdx.x, c = blockIdx.x;
    if (t < NB_C) cur[t] = colbase[t] + hist[(size_t)t * nch + c];
    __syncthreads();
    const int e0 = c * CH, e1 = min(e0 + CH, E);
    for (int e = e0 + t; e < e1; e += 256) {
        int d = dst[e];
        int b = d >> BSH;
        int p = atomicAdd(&cur[b], 1);
        pairs[p] = make_int2(d, src[e]);
    }
}

// ---- pass B: per-bucket CSR build (block = 1024-node bucket) ----
__global__ __launch_bounds__(256) void csrb_kernel(const int2* __restrict__ pairs,
                                                   const int* __restrict__ colbase,
                                                   int* __restrict__ cnt, int* __restrict__ rowptr,
                                                   float* __restrict__ dinv, int* __restrict__ list,
                                                   int N) {
    __shared__ int deg[BN];
    __shared__ int lex[BN];
    __shared__ int s[256];
    const int b = blockIdx.x, t = threadIdx.x;
    const int n0 = b << BSH;
    const int g0 = colbase[b], g1 = colbase[b + 1];
    for (int i = t; i < BN; i += 256) deg[i] = 0;
    __syncthreads();
    for (int i = g0 + t; i < g1; i += 256)
        atomicAdd(&deg[pairs[i].x - n0], 1);
    __syncthreads();
    const int b4 = t * 4;
    const int l0 = deg[b4], l1 = deg[b4 + 1], l2 = deg[b4 + 2], l3 = deg[b4 + 3];
    const int tot = l0 + l1 + l2 + l3;
    s[t] = tot; const int own = tot; __syncthreads();
    for (int off = 1; off < 256; off <<= 1) {
        int a = (t >= off) ? s[t - off] : 0; __syncthreads();
        s[t] += a; __syncthreads();
    }
    const int excl = s[t] - own;
    lex[b4] = excl; lex[b4 + 1] = excl + l0; lex[b4 + 2] = excl + l0 + l1; lex[b4 + 3] = excl + l0 + l1 + l2;
#pragma unroll
    for (int k = 0; k < 4; ++k) {
        int n = n0 + b4 + k;
        if (n < N) {
            int dg = deg[b4 + k];
            cnt[n] = dg;
            rowptr[n] = g0 + lex[b4 + k];
            dinv[n] = rsqrtf((float)dg + 1.0f);
        }
    }
    __syncthreads();
    for (int i = t; i < BN; i += 256) deg[i] = 0;   // reuse as cursors
    __syncthreads();
    for (int i = g0 + t; i < g1; i += 256) {
        int2 pr = pairs[i];
        int ld = pr.x - n0;
        int p = lex[ld] + atomicAdd(&deg[ld], 1);
        list[g0 + p] = pr.y;
    }
}

// ---------------- layer-1 GEMM: out = (x @ W) * dinv, K=256, D=32 ----------------
// BM=256, 256 threads, 4x8 thread tile. BK=16 double-buffered LDS with ONE
// barrier per kc: issue kc+1 loads -> compute buf[p] -> write buf[p^1] -> sync.
// Staging regs: 4 float4 (x) + 1 float4 (W, t<128) = 20 VGPR. Bank-audited:
// xs pitch 20 (rg/rg+8 2-way only), Wk pitch 36 (kk/kk+8 2-way only) = free.
__global__ __launch_bounds__(256) void linear1_kernel(const float* __restrict__ x,
                                                      const float* __restrict__ W,
                                                      const float* __restrict__ dinv,
                                                      float* __restrict__ out, int N) {
    __shared__ float xs[2][256][20];   // 40 KB
    __shared__ float Wk[2][16][36];    // 4.5 KB
    const int t = threadIdx.x;
    const int rg = t >> 2;             // 0..63 : compute rows rg+64i
    const int cg = t & 3;              // cols cg*8..+7
    const int sr = t >> 2;             // staging rows sr+64i
    const int f  = t & 3;              // staging 16B slot within 64B row chunk
    const long row0 = (long)blockIdx.x * 256;

    float4 xst[4];
    float4 wst;
    float acc[4][8] = {};

    auto issue = [&](int kc) {
#pragma unroll
        for (int i = 0; i < 4; ++i) {
            const long gr = row0 + sr + 64 * i;
            xst[i] = (gr < N) ? *(const float4*)(x + gr * F_IN + kc * 16 + f * 4)
                              : make_float4(0.f, 0.f, 0.f, 0.f);
        }
        if (t < 128) wst = *(const float4*)(W + kc * 512 + t * 4);
    };
    auto write_buf = [&](int p) {
#pragma unroll
        for (int i = 0; i < 4; ++i)
            *(float4*)&xs[p][sr + 64 * i][f * 4] = xst[i];
        if (t < 128) {
            const int w = t * 4;             // float index in [0,512)
            *(float4*)&Wk[p][w >> 5][w & 31] = wst;
        }
    };

    issue(0);
    write_buf(0);
    __syncthreads();

    int p = 0;
    for (int kc = 0; kc < 16; ++kc, p ^= 1) {
        if (kc < 15) issue(kc + 1);          // loads in flight during compute
#pragma unroll
        for (int k4 = 0; k4 < 4; ++k4) {
            float4 xr[4];
#pragma unroll
            for (int i = 0; i < 4; ++i) xr[i] = *(float4*)&xs[p][rg + 64 * i][k4 * 4];
#pragma unroll
            for (int j = 0; j < 4; ++j) {
                const int kk = k4 * 4 + j;
                const float4 w0 = *(float4*)&Wk[p][kk][cg * 8];
                const float4 w1 = *(float4*)&Wk[p][kk][cg * 8 + 4];
#pragma unroll
                for (int i = 0; i < 4; ++i) {
                    const float xv = (j == 0) ? xr[i].x : (j == 1) ? xr[i].y
                                   : (j == 2) ? xr[i].z : xr[i].w;
                    acc[i][0] += xv * w0.x; acc[i][1] += xv * w0.y;
                    acc[i][2] += xv * w0.z; acc[i][3] += xv * w0.w;
                    acc[i][4] += xv * w1.x; acc[i][5] += xv * w1.y;
                    acc[i][6] += xv * w1.z; acc[i][7] += xv * w1.w;
                }
            }
        }
        if (kc < 15) write_buf(p ^ 1);       // safe: readers are on buf[p]
        __syncthreads();
    }
#pragma unroll
    for (int i = 0; i < 4; ++i) {
        const long r = row0 + rg + 64 * i;
        if (r >= N) continue;
        const float dv = dinv[r];
        float4 o0 = make_float4(acc[i][0] * dv, acc[i][1] * dv, acc[i][2] * dv, acc[i][3] * dv);
        float4 o1 = make_float4(acc[i][4] * dv, acc[i][5] * dv, acc[i][6] * dv, acc[i][7] * dv);
        *(float4*)(out + r * 32 + cg * 8) = o0;
        *(float4*)(out + r * 32 + cg * 8 + 4) = o1;
    }
}

// ---------------- small linear: out = (x @ W) * dinv, thread per row ----------------
template <int K, int D>
__global__ void linear_small_kernel(const float* __restrict__ x, const float* __restrict__ W,
                                    const float* __restrict__ dinv, float* __restrict__ out, int N) {
    __shared__ float Ws[K * D];
    const int t = threadIdx.x;
    for (int i = t; i < K * D; i += 256) Ws[i] = W[i];
    __syncthreads();
    long row = (long)blockIdx.x * 256 + t;
    if (row >= N) return;
    float acc[D] = {};
    const float4* xr = (const float4*)(x + row * K);
#pragma unroll
    for (int k4 = 0; k4 < K / 4; ++k4) {
        float4 xv = xr[k4];
        float xvs[4] = {xv.x, xv.y, xv.z, xv.w};
#pragma unroll
        for (int j = 0; j < 4; ++j) {
#pragma unroll
            for (int c4 = 0; c4 < D / 4; ++c4) {
                float4 w = *(const float4*)&Ws[(k4 * 4 + j) * D + c4 * 4];
                acc[c4 * 4 + 0] += xvs[j] * w.x;
                acc[c4 * 4 + 1] += xvs[j] * w.y;
                acc[c4 * 4 + 2] += xvs[j] * w.z;
                acc[c4 * 4 + 3] += xvs[j] * w.w;
            }
        }
    }
    float dv = dinv[row];
#pragma unroll
    for (int c4 = 0; c4 < D / 4; ++c4) {
        float4 o = make_float4(acc[c4 * 4 + 0] * dv, acc[c4 * 4 + 1] * dv,
                               acc[c4 * 4 + 2] * dv, acc[c4 * 4 + 3] * dv);
        *(float4*)(out + row * D + c4 * 4) = o;
    }
}

// ---------------- gather: out_i = tanh(dinv_i*(hs_i + sum hs_src) + b) ----------------
template <int D>
__global__ void gather_kernel(const int* __restrict__ rowptr, const int* __restrict__ cnt,
                              const int* __restrict__ list, const float* __restrict__ hs,
                              const float* __restrict__ dinv, const float* __restrict__ b,
                              float* __restrict__ out, int N) {
    constexpr int L = D / 4;
    constexpr int GPB = 256 / L;
    const int t = threadIdx.x;
    const int g = t / L, lane = t % L;
    long node = (long)blockIdx.x * GPB + g;
    if (node >= N) return;
    const int start = rowptr[node];
    const int num = cnt[node];
    const int* __restrict__ lp = list + start;
    const float4* __restrict__ hs4 = (const float4*)hs;
    float4 acc = hs4[node * L + lane];
    int j = 0;
    for (; j + 8 <= num; j += 8) {
        int s0 = lp[j], s1 = lp[j + 1], s2 = lp[j + 2], s3 = lp[j + 3];
        int s4 = lp[j + 4], s5 = lp[j + 5], s6 = lp[j + 6], s7 = lp[j + 7];
        float4 v0 = hs4[(long)s0 * L + lane], v1 = hs4[(long)s1 * L + lane];
        float4 v2 = hs4[(long)s2 * L + lane], v3 = hs4[(long)s3 * L + lane];
        float4 v4 = hs4[(long)s4 * L + lane], v5 = hs4[(long)s5 * L + lane];
        float4 v6 = hs4[(long)s6 * L + lane], v7 = hs4[(long)s7 * L + lane];
        acc.x += ((v0.x + v1.x) + (v2.x + v3.x)) + ((v4.x + v5.x) + (v6.x + v7.x));
        acc.y += ((v0.y + v1.y) + (v2.y + v3.y)) + ((v4.y + v5.y) + (v6.y + v7.y));
        acc.z += ((v0.z + v1.z) + (v2.z + v3.z)) + ((v4.z + v5.z) + (v6.z + v7.z));
        acc.w += ((v0.w + v1.w) + (v2.w + v3.w)) + ((v4.w + v5.w) + (v6.w + v7.w));
    }
    for (; j < num; ++j) {
        int s = lp[j];
        float4 v = hs4[(long)s * L + lane];
        acc.x += v.x; acc.y += v.y; acc.z += v.z; acc.w += v.w;
    }
    const float dv = dinv[node];
    const float4 bb = *(const float4*)(b + lane * 4);
    float4 o;
    o.x = tanhf(acc.x * dv + bb.x);
    o.y = tanhf(acc.y * dv + bb.y);
    o.z = tanhf(acc.z * dv + bb.z);
    o.w = tanhf(acc.w * dv + bb.w);
    *(float4*)(out + node * D + lane * 4) = o;
}

// ---------------- D=8 gather fused with classifier ----------------
__global__ void gather8_final_kernel(const int* __restrict__ rowptr, const int* __restrict__ cnt,
                                     const int* __restrict__ list, const float* __restrict__ hs,
                                     const float* __restrict__ dinv, const float* __restrict__ b,
                                     const float* __restrict__ Wc, const float* __restrict__ bc,
                                     float* __restrict__ out, int N) {
    const int t = threadIdx.x;
    const int g = t >> 1, lane = t & 1;
    long node = (long)blockIdx.x * 128 + g;
    if (node >= N) return;
    const int start = rowptr[node];
    const int num = cnt[node];
    const int* __restrict__ lp = list + start;
    const float4* __restrict__ hs4 = (const float4*)hs;
    float4 acc = hs4[node * 2 + lane];
    int j = 0;
    for (; j + 8 <= num; j += 8) {
        int s0 = lp[j], s1 = lp[j + 1], s2 = lp[j + 2], s3 = lp[j + 3];
        int s4 = lp[j + 4], s5 = lp[j + 5], s6 = lp[j + 6], s7 = lp[j + 7];
        float4 v0 = hs4[(long)s0 * 2 + lane], v1 = hs4[(long)s1 * 2 + lane];
        float4 v2 = hs4[(long)s2 * 2 + lane], v3 = hs4[(long)s3 * 2 + lane];
        float4 v4 = hs4[(long)s4 * 2 + lane], v5 = hs4[(long)s5 * 2 + lane];
        float4 v6 = hs4[(long)s6 * 2 + lane], v7 = hs4[(long)s7 * 2 + lane];
        acc.x += ((v0.x + v1.x) + (v2.x + v3.x)) + ((v4.x + v5.x) + (v6.x + v7.x));
        acc.y += ((v0.y + v1.y) + (v2.y + v3.y)) + ((v4.y + v5.y) + (v6.y + v7.y));
        acc.z += ((v0.z + v1.z) + (v2.z + v3.z)) + ((v4.z + v5.z) + (v6.z + v7.z));
        acc.w += ((v0.w + v1.w) + (v2.w + v3.w)) + ((v4.w + v5.w) + (v6.w + v7.w));
    }
    for (; j < num; ++j) {
        int s = lp[j];
        float4 v = hs4[(long)s * 2 + lane];
        acc.x += v.x; acc.y += v.y; acc.z += v.z; acc.w += v.w;
    }
    const float dv = dinv[node];
    const float4 bb = *(const float4*)(b + lane * 4);
    float4 h;
    h.x = tanhf(acc.x * dv + bb.x);
    h.y = tanhf(acc.y * dv + bb.y);
    h.z = tanhf(acc.z * dv + bb.z);
    h.w = tanhf(acc.w * dv + bb.w);
    const float4 w0 = *(const float4*)(Wc + (lane * 4 + 0) * 4);
    const float4 w1 = *(const float4*)(Wc + (lane * 4 + 1) * 4);
    const float4 w2 = *(const float4*)(Wc + (lane * 4 + 2) * 4);
    const float4 w3 = *(const float4*)(Wc + (lane * 4 + 3) * 4);
    float4 p;
    p.x = h.x * w0.x + h.y * w1.x + h.z * w2.x + h.w * w3.x;
    p.y = h.x * w0.y + h.y * w1.y + h.z * w2.y + h.w * w3.y;
    p.z = h.x * w0.z + h.y * w1.z + h.z * w2.z + h.w * w3.z;
    p.w = h.x * w0.w + h.y * w1.w + h.z * w2.w + h.w * w3.w;
    p.x += __shfl_xor(p.x, 1);
    p.y += __shfl_xor(p.y, 1);
    p.z += __shfl_xor(p.z, 1);
    p.w += __shfl_xor(p.w, 1);
    if (lane == 0) {
        const float4 bcv = *(const float4*)bc;
        float4 o = make_float4(p.x + bcv.x, p.y + bcv.y, p.z + bcv.z, p.w + bcv.w);
        *(float4*)(out + node * 4) = o;
    }
}

extern "C" void kernel_launch(void* const* d_in, const int* in_sizes, int n_in,
                              void* d_out, int out_size, void* d_ws, size_t ws_size,
                              hipStream_t stream) {
    const float* x  = (const float*)d_in[0];
    const int*   ei = (const int*)d_in[1];
    const float* W1 = (const float*)d_in[2];
    const float* b1 = (const float*)d_in[3];
    const float* W2 = (const float*)d_in[4];
    const float* b2 = (const float*)d_in[5];
    const float* W3 = (const float*)d_in[6];
    const float* b3 = (const float*)d_in[7];
    const float* Wc = (const float*)d_in[8];
    const float* bc = (const float*)d_in[9];
    float* out = (float*)d_out;

    const int N = in_sizes[0] / F_IN;
    const int E = in_sizes[1] / 2;
    const int* src = ei;
    const int* dst = ei + E;
    const int B = 256;

    const int NB_C = (N + BN - 1) >> BSH;       // coarse buckets (196) <= 256
    const int nch  = (E + CH - 1) / CH;         // chunks (391)

    char* p = (char*)d_ws;
    auto take = [&](size_t bytes) { char* q = p; p += (bytes + 255) & ~size_t(255); return q; };
    int*   cnt     = (int*)take((size_t)N * 4);
    int*   rowptr  = (int*)take((size_t)N * 4);
    float* dinv    = (float*)take((size_t)N * 4);
    int*   hist    = (int*)take((size_t)NB_C * nch * 4);
    int*   btotal  = (int*)take((size_t)NB_C * 4);
    int*   colbase = (int*)take((size_t)(NB_C + 1) * 4);
    int*   list    = (int*)take((size_t)E * 4);
    float* bufA    = (float*)take((size_t)N * 32 * 4);
    float* bufB    = (float*)take((size_t)N * 32 * 4);
    int2*  pairs   = (int2*)bufA;   // alias: pairs dead before linear1 writes bufA

    // ---- CSR build (deterministic two-level counting sort) ----
    histc_kernel<<<nch, B, 0, stream>>>(dst, hist, NB_C, nch, E);
    scanb_kernel<<<NB_C, B, 0, stream>>>(hist, btotal, nch);
    scanc_kernel<<<1, B, 0, stream>>>(btotal, colbase, NB_C);
    scat_kernel<<<nch, B, 0, stream>>>(src, dst, hist, colbase, pairs, NB_C, nch, E);
    csrb_kernel<<<NB_C, B, 0, stream>>>(pairs, colbase, cnt, rowptr, dinv, list, N);

    // ---- layer 1: 256 -> 32 ----
    linear1_kernel<<<(N + 255) / 256, B, 0, stream>>>(x, W1, dinv, bufA, N);
    gather_kernel<32><<<(N + 31) / 32, B, 0, stream>>>(rowptr, cnt, list, bufA, dinv, b1, bufB, N);
    // ---- layer 2: 32 -> 16 ----
    linear_small_kernel<32, 16><<<(N + 255) / 256, B, 0, stream>>>(bufB, W2, dinv, bufA, N);
    gather_kernel<16><<<(N + 63) / 64, B, 0, stream>>>(rowptr, cnt, list, bufA, dinv, b2, bufB, N);
    // ---- layer 3: 16 -> 8, classifier fused ----
    linear_small_kernel<16, 8><<<(N + 255) / 256, B, 0, stream>>>(bufB, W3, dinv, bufA, N);
    gather8_final_kernel<<<(N + 127) / 128, B, 0, stream>>>(rowptr, cnt, list, bufA, dinv, b3, Wc, bc, out, N);
}

// Round 10
// 332.717 us; speedup vs baseline: 2.0338x; 1.0734x over previous
//
#include <hip/hip_runtime.h>

// GCN: 3x (linear -> symmetric-norm conv -> bias -> tanh) -> linear.
// N=200000, E=3200000, F=256->32->16->8->4, fp32.
// Round 10: (a) linear2/linear3 fused into gather epilogues via width-8/4
// shuffle broadcast (deletes both linear_small kernels); (b) CSR pairs packed
// into one int ((local_dst<<18)|src, valid for N<=2^18) halving sort traffic.
// linear1 = round-9 single-barrier dbuf. CSR = deterministic 2-level sort.
// Algebra: norm = dinv[s]*dinv[d]  =>  agg_i = dinv_i * (hs_i + sum_in hs_src)
// with hs = (h @ W) * dinv folded into the producing kernel's epilogue.

constexpr int F_IN = 256;
constexpr int BSH = 10;            // nodes per coarse bucket = 1024
constexpr int BN  = 1 << BSH;
constexpr int CH  = 8192;          // edges per chunk
constexpr int SRC_BITS = 18;       // N=200000 < 2^18
constexpr int SRC_MASK = (1 << SRC_BITS) - 1;

// ---- pass A1: per-chunk bucket histogram (transposed store: hist[b][c]) ----
__global__ void histc_kernel(const int* __restrict__ dst, int* __restrict__ hist,
                             int NB_C, int nch, int E) {
    __shared__ int h[256];
    const int t = threadIdx.x, c = blockIdx.x;
    h[t] = 0; __syncthreads();
    const int e0 = c * CH, e1 = min(e0 + CH, E);
    for (int e = e0 + t; e < e1; e += 256)
        atomicAdd(&h[dst[e] >> BSH], 1);
    __syncthreads();
    if (t < NB_C) hist[(size_t)t * nch + c] = h[t];
}

// ---- pass A2: exclusive scan of each bucket row (in place), total -> btotal ----
__global__ void scanb_kernel(int* __restrict__ hist, int* __restrict__ btotal, int nch) {
    __shared__ int s[256];
    const int b = blockIdx.x, t = threadIdx.x;
    int* row = hist + (size_t)b * nch;
    const int K = (nch + 255) / 256;
    int loc[8]; int tot = 0;
    for (int i = 0; i < K; ++i) {
        int idx = t * K + i;
        int v = (idx < nch) ? row[idx] : 0;
        loc[i] = tot; tot += v;
    }
    s[t] = tot; const int own = tot; __syncthreads();
    for (int off = 1; off < 256; off <<= 1) {
        int a = (t >= off) ? s[t - off] : 0; __syncthreads();
        s[t] += a; __syncthreads();
    }
    const int excl = s[t] - own;
    for (int i = 0; i < K; ++i) {
        int idx = t * K + i;
        if (idx < nch) row[idx] = excl + loc[i];
    }
    if (t == 255) btotal[b] = s[255];
}

// ---- pass A3: exclusive scan of bucket totals -> colbase[NB_C+1] ----
__global__ void scanc_kernel(const int* __restrict__ btotal, int* __restrict__ colbase, int NB_C) {
    __shared__ int s[256];
    const int t = threadIdx.x;
    int v = (t < NB_C) ? btotal[t] : 0;
    s[t] = v; const int own = v; __syncthreads();
    for (int off = 1; off < 256; off <<= 1) {
        int a = (t >= off) ? s[t - off] : 0; __syncthreads();
        s[t] += a; __syncthreads();
    }
    if (t < NB_C) colbase[t] = s[t] - own;
    if (t == 255) colbase[NB_C] = s[255];
}

// ---- pass A4: scatter packed (local_dst<<18)|src to exact slots ----
__global__ void scat_kernel(const int* __restrict__ src, const int* __restrict__ dst,
                            const int* __restrict__ hist, const int* __restrict__ colbase,
                            int* __restrict__ pairs, int NB_C, int nch, int E) {
    __shared__ int cur[256];
    const int t = threadIdx.x, c = blockIdx.x;
    if (t < NB_C) cur[t] = colbase[t] + hist[(size_t)t * nch + c];
    __syncthreads();
    const int e0 = c * CH, e1 = min(e0 + CH, E);
    for (int e = e0 + t; e < e1; e += 256) {
        int d = dst[e];
        int b = d >> BSH;
        int p = atomicAdd(&cur[b], 1);
        pairs[p] = ((d & (BN - 1)) << SRC_BITS) | src[e];
    }
}

// ---- pass B: per-bucket CSR build (block = 1024-node bucket) ----
__global__ __launch_bounds__(256) void csrb_kernel(const int* __restrict__ pairs,
                                                   const int* __restrict__ colbase,
                                                   int* __restrict__ cnt, int* __restrict__ rowptr,
                                                   float* __restrict__ dinv, int* __restrict__ list,
                                                   int N) {
    __shared__ int deg[BN];
    __shared__ int lex[BN];
    __shared__ int s[256];
    const int b = blockIdx.x, t = threadIdx.x;
    const int n0 = b << BSH;
    const int g0 = colbase[b], g1 = colbase[b + 1];
    for (int i = t; i < BN; i += 256) deg[i] = 0;
    __syncthreads();
    for (int i = g0 + t; i < g1; i += 256)
        atomicAdd(&deg[pairs[i] >> SRC_BITS], 1);
    __syncthreads();
    const int b4 = t * 4;
    const int l0 = deg[b4], l1 = deg[b4 + 1], l2 = deg[b4 + 2], l3 = deg[b4 + 3];
    const int tot = l0 + l1 + l2 + l3;
    s[t] = tot; const int own = tot; __syncthreads();
    for (int off = 1; off < 256; off <<= 1) {
        int a = (t >= off) ? s[t - off] : 0; __syncthreads();
        s[t] += a; __syncthreads();
    }
    const int excl = s[t] - own;
    lex[b4] = excl; lex[b4 + 1] = excl + l0; lex[b4 + 2] = excl + l0 + l1; lex[b4 + 3] = excl + l0 + l1 + l2;
#pragma unroll
    for (int k = 0; k < 4; ++k) {
        int n = n0 + b4 + k;
        if (n < N) {
            int dg = deg[b4 + k];
            cnt[n] = dg;
            rowptr[n] = g0 + lex[b4 + k];
            dinv[n] = rsqrtf((float)dg + 1.0f);
        }
    }
    __syncthreads();
    for (int i = t; i < BN; i += 256) deg[i] = 0;   // reuse as cursors
    __syncthreads();
    for (int i = g0 + t; i < g1; i += 256) {
        int pr = pairs[i];
        int ld = pr >> SRC_BITS;
        int p = lex[ld] + atomicAdd(&deg[ld], 1);
        list[g0 + p] = pr & SRC_MASK;
    }
}

// ---------------- layer-1 GEMM: out = (x @ W) * dinv (round-9 v5) ----------------
__global__ __launch_bounds__(256) void linear1_kernel(const float* __restrict__ x,
                                                      const float* __restrict__ W,
                                                      const float* __restrict__ dinv,
                                                      float* __restrict__ out, int N) {
    __shared__ float xs[2][256][20];   // 40 KB
    __shared__ float Wk[2][16][36];    // 4.5 KB
    const int t = threadIdx.x;
    const int rg = t >> 2;             // 0..63 : compute rows rg+64i
    const int cg = t & 3;              // cols cg*8..+7
    const int sr = t >> 2;             // staging rows sr+64i
    const int f  = t & 3;              // staging 16B slot within 64B row chunk
    const long row0 = (long)blockIdx.x * 256;

    float4 xst[4];
    float4 wst;
    float acc[4][8] = {};

    auto issue = [&](int kc) {
#pragma unroll
        for (int i = 0; i < 4; ++i) {
            const long gr = row0 + sr + 64 * i;
            xst[i] = (gr < N) ? *(const float4*)(x + gr * F_IN + kc * 16 + f * 4)
                              : make_float4(0.f, 0.f, 0.f, 0.f);
        }
        if (t < 128) wst = *(const float4*)(W + kc * 512 + t * 4);
    };
    auto write_buf = [&](int p) {
#pragma unroll
        for (int i = 0; i < 4; ++i)
            *(float4*)&xs[p][sr + 64 * i][f * 4] = xst[i];
        if (t < 128) {
            const int w = t * 4;
            *(float4*)&Wk[p][w >> 5][w & 31] = wst;
        }
    };

    issue(0);
    write_buf(0);
    __syncthreads();

    int p = 0;
    for (int kc = 0; kc < 16; ++kc, p ^= 1) {
        if (kc < 15) issue(kc + 1);
#pragma unroll
        for (int k4 = 0; k4 < 4; ++k4) {
            float4 xr[4];
#pragma unroll
            for (int i = 0; i < 4; ++i) xr[i] = *(float4*)&xs[p][rg + 64 * i][k4 * 4];
#pragma unroll
            for (int j = 0; j < 4; ++j) {
                const int kk = k4 * 4 + j;
                const float4 w0 = *(float4*)&Wk[p][kk][cg * 8];
                const float4 w1 = *(float4*)&Wk[p][kk][cg * 8 + 4];
#pragma unroll
                for (int i = 0; i < 4; ++i) {
                    const float xv = (j == 0) ? xr[i].x : (j == 1) ? xr[i].y
                                   : (j == 2) ? xr[i].z : xr[i].w;
                    acc[i][0] += xv * w0.x; acc[i][1] += xv * w0.y;
                    acc[i][2] += xv * w0.z; acc[i][3] += xv * w0.w;
                    acc[i][4] += xv * w1.x; acc[i][5] += xv * w1.y;
                    acc[i][6] += xv * w1.z; acc[i][7] += xv * w1.w;
                }
            }
        }
        if (kc < 15) write_buf(p ^ 1);
        __syncthreads();
    }
#pragma unroll
    for (int i = 0; i < 4; ++i) {
        const long r = row0 + rg + 64 * i;
        if (r >= N) continue;
        const float dv = dinv[r];
        float4 o0 = make_float4(acc[i][0] * dv, acc[i][1] * dv, acc[i][2] * dv, acc[i][3] * dv);
        float4 o1 = make_float4(acc[i][4] * dv, acc[i][5] * dv, acc[i][6] * dv, acc[i][7] * dv);
        *(float4*)(out + r * 32 + cg * 8) = o0;
        *(float4*)(out + r * 32 + cg * 8 + 4) = o1;
    }
}

// ---- gather D=32 + fused linear2: out = (tanh(dinv*(hs_i+sum)+b1) @ W2) * dinv ----
// 8 lanes/node, lane owns float4 channels. Epilogue: width-8 shuffle broadcast
// of h across the group; each lane computes 2 of 16 output channels.
__global__ void gather32_lin2_kernel(const int* __restrict__ rowptr, const int* __restrict__ cnt,
                                     const int* __restrict__ list, const float* __restrict__ hs,
                                     const float* __restrict__ dinv, const float* __restrict__ b1,
                                     const float* __restrict__ W2, float* __restrict__ out, int N) {
    __shared__ float W2s[32][16];
    const int t = threadIdx.x;
    if (t < 128) ((float4*)&W2s[0][0])[t] = ((const float4*)W2)[t];
    __syncthreads();
    const int g = t >> 3, lane = t & 7;
    long node = (long)blockIdx.x * 32 + g;
    if (node >= N) return;
    const int start = rowptr[node];
    const int num = cnt[node];
    const int* __restrict__ lp = list + start;
    const float4* __restrict__ hs4 = (const float4*)hs;
    float4 acc = hs4[node * 8 + lane];
    int j = 0;
    for (; j + 8 <= num; j += 8) {
        int s0 = lp[j], s1 = lp[j + 1], s2 = lp[j + 2], s3 = lp[j + 3];
        int s4 = lp[j + 4], s5 = lp[j + 5], s6 = lp[j + 6], s7 = lp[j + 7];
        float4 v0 = hs4[(long)s0 * 8 + lane], v1 = hs4[(long)s1 * 8 + lane];
        float4 v2 = hs4[(long)s2 * 8 + lane], v3 = hs4[(long)s3 * 8 + lane];
        float4 v4 = hs4[(long)s4 * 8 + lane], v5 = hs4[(long)s5 * 8 + lane];
        float4 v6 = hs4[(long)s6 * 8 + lane], v7 = hs4[(long)s7 * 8 + lane];
        acc.x += ((v0.x + v1.x) + (v2.x + v3.x)) + ((v4.x + v5.x) + (v6.x + v7.x));
        acc.y += ((v0.y + v1.y) + (v2.y + v3.y)) + ((v4.y + v5.y) + (v6.y + v7.y));
        acc.z += ((v0.z + v1.z) + (v2.z + v3.z)) + ((v4.z + v5.z) + (v6.z + v7.z));
        acc.w += ((v0.w + v1.w) + (v2.w + v3.w)) + ((v4.w + v5.w) + (v6.w + v7.w));
    }
    for (; j < num; ++j) {
        int s = lp[j];
        float4 v = hs4[(long)s * 8 + lane];
        acc.x += v.x; acc.y += v.y; acc.z += v.z; acc.w += v.w;
    }
    const float dv = dinv[node];
    const float4 bb = *(const float4*)(b1 + lane * 4);
    float4 h;
    h.x = tanhf(acc.x * dv + bb.x);
    h.y = tanhf(acc.y * dv + bb.y);
    h.z = tanhf(acc.z * dv + bb.z);
    h.w = tanhf(acc.w * dv + bb.w);
    // fused linear2: lane computes output channels c0, c0+1
    const int c0 = lane * 2;
    float o0 = 0.f, o1 = 0.f;
#pragma unroll
    for (int gk = 0; gk < 8; ++gk) {
        const float a0 = __shfl(h.x, gk, 8);
        const float a1 = __shfl(h.y, gk, 8);
        const float a2 = __shfl(h.z, gk, 8);
        const float a3 = __shfl(h.w, gk, 8);
        o0 += a0 * W2s[gk * 4 + 0][c0] + a1 * W2s[gk * 4 + 1][c0]
            + a2 * W2s[gk * 4 + 2][c0] + a3 * W2s[gk * 4 + 3][c0];
        o1 += a0 * W2s[gk * 4 + 0][c0 + 1] + a1 * W2s[gk * 4 + 1][c0 + 1]
            + a2 * W2s[gk * 4 + 2][c0 + 1] + a3 * W2s[gk * 4 + 3][c0 + 1];
    }
    *(float2*)(out + node * 16 + c0) = make_float2(o0 * dv, o1 * dv);
}

// ---- gather D=16 + fused linear3: 4 lanes/node, width-4 shuffles, W3[16][8] ----
__global__ void gather16_lin3_kernel(const int* __restrict__ rowptr, const int* __restrict__ cnt,
                                     const int* __restrict__ list, const float* __restrict__ hs,
                                     const float* __restrict__ dinv, const float* __restrict__ b2,
                                     const float* __restrict__ W3, float* __restrict__ out, int N) {
    __shared__ float W3s[16][8];
    const int t = threadIdx.x;
    if (t < 32) ((float4*)&W3s[0][0])[t] = ((const float4*)W3)[t];
    __syncthreads();
    const int g = t >> 2, lane = t & 3;
    long node = (long)blockIdx.x * 64 + g;
    if (node >= N) return;
    const int start = rowptr[node];
    const int num = cnt[node];
    const int* __restrict__ lp = list + start;
    const float4* __restrict__ hs4 = (const float4*)hs;
    float4 acc = hs4[node * 4 + lane];
    int j = 0;
    for (; j + 8 <= num; j += 8) {
        int s0 = lp[j], s1 = lp[j + 1], s2 = lp[j + 2], s3 = lp[j + 3];
        int s4 = lp[j + 4], s5 = lp[j + 5], s6 = lp[j + 6], s7 = lp[j + 7];
        float4 v0 = hs4[(long)s0 * 4 + lane], v1 = hs4[(long)s1 * 4 + lane];
        float4 v2 = hs4[(long)s2 * 4 + lane], v3 = hs4[(long)s3 * 4 + lane];
        float4 v4 = hs4[(long)s4 * 4 + lane], v5 = hs4[(long)s5 * 4 + lane];
        float4 v6 = hs4[(long)s6 * 4 + lane], v7 = hs4[(long)s7 * 4 + lane];
        acc.x += ((v0.x + v1.x) + (v2.x + v3.x)) + ((v4.x + v5.x) + (v6.x + v7.x));
        acc.y += ((v0.y + v1.y) + (v2.y + v3.y)) + ((v4.y + v5.y) + (v6.y + v7.y));
        acc.z += ((v0.z + v1.z) + (v2.z + v3.z)) + ((v4.z + v5.z) + (v6.z + v7.z));
        acc.w += ((v0.w + v1.w) + (v2.w + v3.w)) + ((v4.w + v5.w) + (v6.w + v7.w));
    }
    for (; j < num; ++j) {
        int s = lp[j];
        float4 v = hs4[(long)s * 4 + lane];
        acc.x += v.x; acc.y += v.y; acc.z += v.z; acc.w += v.w;
    }
    const float dv = dinv[node];
    const float4 bb = *(const float4*)(b2 + lane * 4);
    float4 h;
    h.x = tanhf(acc.x * dv + bb.x);
    h.y = tanhf(acc.y * dv + bb.y);
    h.z = tanhf(acc.z * dv + bb.z);
    h.w = tanhf(acc.w * dv + bb.w);
    const int c0 = lane * 2;
    float o0 = 0.f, o1 = 0.f;
#pragma unroll
    for (int gk = 0; gk < 4; ++gk) {
        const float a0 = __shfl(h.x, gk, 4);
        const float a1 = __shfl(h.y, gk, 4);
        const float a2 = __shfl(h.z, gk, 4);
        const float a3 = __shfl(h.w, gk, 4);
        o0 += a0 * W3s[gk * 4 + 0][c0] + a1 * W3s[gk * 4 + 1][c0]
            + a2 * W3s[gk * 4 + 2][c0] + a3 * W3s[gk * 4 + 3][c0];
        o1 += a0 * W3s[gk * 4 + 0][c0 + 1] + a1 * W3s[gk * 4 + 1][c0 + 1]
            + a2 * W3s[gk * 4 + 2][c0 + 1] + a3 * W3s[gk * 4 + 3][c0 + 1];
    }
    *(float2*)(out + node * 8 + c0) = make_float2(o0 * dv, o1 * dv);
}

// ---------------- D=8 gather fused with classifier ----------------
__global__ void gather8_final_kernel(const int* __restrict__ rowptr, const int* __restrict__ cnt,
                                     const int* __restrict__ list, const float* __restrict__ hs,
                                     const float* __restrict__ dinv, const float* __restrict__ b,
                                     const float* __restrict__ Wc, const float* __restrict__ bc,
                                     float* __restrict__ out, int N) {
    const int t = threadIdx.x;
    const int g = t >> 1, lane = t & 1;
    long node = (long)blockIdx.x * 128 + g;
    if (node >= N) return;
    const int start = rowptr[node];
    const int num = cnt[node];
    const int* __restrict__ lp = list + start;
    const float4* __restrict__ hs4 = (const float4*)hs;
    float4 acc = hs4[node * 2 + lane];
    int j = 0;
    for (; j + 8 <= num; j += 8) {
        int s0 = lp[j], s1 = lp[j + 1], s2 = lp[j + 2], s3 = lp[j + 3];
        int s4 = lp[j + 4], s5 = lp[j + 5], s6 = lp[j + 6], s7 = lp[j + 7];
        float4 v0 = hs4[(long)s0 * 2 + lane], v1 = hs4[(long)s1 * 2 + lane];
        float4 v2 = hs4[(long)s2 * 2 + lane], v3 = hs4[(long)s3 * 2 + lane];
        float4 v4 = hs4[(long)s4 * 2 + lane], v5 = hs4[(long)s5 * 2 + lane];
        float4 v6 = hs4[(long)s6 * 2 + lane], v7 = hs4[(long)s7 * 2 + lane];
        acc.x += ((v0.x + v1.x) + (v2.x + v3.x)) + ((v4.x + v5.x) + (v6.x + v7.x));
        acc.y += ((v0.y + v1.y) + (v2.y + v3.y)) + ((v4.y + v5.y) + (v6.y + v7.y));
        acc.z += ((v0.z + v1.z) + (v2.z + v3.z)) + ((v4.z + v5.z) + (v6.z + v7.z));
        acc.w += ((v0.w + v1.w) + (v2.w + v3.w)) + ((v4.w + v5.w) + (v6.w + v7.w));
    }
    for (; j < num; ++j) {
        int s = lp[j];
        float4 v = hs4[(long)s * 2 + lane];
        acc.x += v.x; acc.y += v.y; acc.z += v.z; acc.w += v.w;
    }
    const float dv = dinv[node];
    const float4 bb = *(const float4*)(b + lane * 4);
    float4 h;
    h.x = tanhf(acc.x * dv + bb.x);
    h.y = tanhf(acc.y * dv + bb.y);
    h.z = tanhf(acc.z * dv + bb.z);
    h.w = tanhf(acc.w * dv + bb.w);
    const float4 w0 = *(const float4*)(Wc + (lane * 4 + 0) * 4);
    const float4 w1 = *(const float4*)(Wc + (lane * 4 + 1) * 4);
    const float4 w2 = *(const float4*)(Wc + (lane * 4 + 2) * 4);
    const float4 w3 = *(const float4*)(Wc + (lane * 4 + 3) * 4);
    float4 p;
    p.x = h.x * w0.x + h.y * w1.x + h.z * w2.x + h.w * w3.x;
    p.y = h.x * w0.y + h.y * w1.y + h.z * w2.y + h.w * w3.y;
    p.z = h.x * w0.z + h.y * w1.z + h.z * w2.z + h.w * w3.z;
    p.w = h.x * w0.w + h.y * w1.w + h.z * w2.w + h.w * w3.w;
    p.x += __shfl_xor(p.x, 1);
    p.y += __shfl_xor(p.y, 1);
    p.z += __shfl_xor(p.z, 1);
    p.w += __shfl_xor(p.w, 1);
    if (lane == 0) {
        const float4 bcv = *(const float4*)bc;
        float4 o = make_float4(p.x + bcv.x, p.y + bcv.y, p.z + bcv.z, p.w + bcv.w);
        *(float4*)(out + node * 4) = o;
    }
}

extern "C" void kernel_launch(void* const* d_in, const int* in_sizes, int n_in,
                              void* d_out, int out_size, void* d_ws, size_t ws_size,
                              hipStream_t stream) {
    const float* x  = (const float*)d_in[0];
    const int*   ei = (const int*)d_in[1];
    const float* W1 = (const float*)d_in[2];
    const float* b1 = (const float*)d_in[3];
    const float* W2 = (const float*)d_in[4];
    const float* b2 = (const float*)d_in[5];
    const float* W3 = (const float*)d_in[6];
    const float* b3 = (const float*)d_in[7];
    const float* Wc = (const float*)d_in[8];
    const float* bc = (const float*)d_in[9];
    float* out = (float*)d_out;

    const int N = in_sizes[0] / F_IN;
    const int E = in_sizes[1] / 2;
    const int* src = ei;
    const int* dst = ei + E;
    const int B = 256;

    const int NB_C = (N + BN - 1) >> BSH;       // coarse buckets (196) <= 256
    const int nch  = (E + CH - 1) / CH;         // chunks (391)

    char* p = (char*)d_ws;
    auto take = [&](size_t bytes) { char* q = p; p += (bytes + 255) & ~size_t(255); return q; };
    int*   cnt     = (int*)take((size_t)N * 4);
    int*   rowptr  = (int*)take((size_t)N * 4);
    float* dinv    = (float*)take((size_t)N * 4);
    int*   hist    = (int*)take((size_t)NB_C * nch * 4);
    int*   btotal  = (int*)take((size_t)NB_C * 4);
    int*   colbase = (int*)take((size_t)(NB_C + 1) * 4);
    int*   list    = (int*)take((size_t)E * 4);
    float* bufA    = (float*)take((size_t)N * 32 * 4);
    float* bufB    = (float*)take((size_t)N * 32 * 4);
    int*   pairs   = (int*)bufA;   // alias: pairs dead before linear1 writes bufA

    // ---- CSR build (deterministic two-level counting sort, packed pairs) ----
    histc_kernel<<<nch, B, 0, stream>>>(dst, hist, NB_C, nch, E);
    scanb_kernel<<<NB_C, B, 0, stream>>>(hist, btotal, nch);
    scanc_kernel<<<1, B, 0, stream>>>(btotal, colbase, NB_C);
    scat_kernel<<<nch, B, 0, stream>>>(src, dst, hist, colbase, pairs, NB_C, nch, E);
    csrb_kernel<<<NB_C, B, 0, stream>>>(pairs, colbase, cnt, rowptr, dinv, list, N);

    // ---- layer 1: 256 -> 32 ----
    linear1_kernel<<<(N + 255) / 256, B, 0, stream>>>(x, W1, dinv, bufA, N);
    // ---- layer 1 conv + layer 2 linear fused ----
    gather32_lin2_kernel<<<(N + 31) / 32, B, 0, stream>>>(rowptr, cnt, list, bufA, dinv, b1, W2, bufB, N);
    // ---- layer 2 conv + layer 3 linear fused ----
    gather16_lin3_kernel<<<(N + 63) / 64, B, 0, stream>>>(rowptr, cnt, list, bufB, dinv, b2, W3, bufA, N);
    // ---- layer 3 conv + classifier fused ----
    gather8_final_kernel<<<(N + 127) / 128, B, 0, stream>>>(rowptr, cnt, list, bufA, dinv, b3, Wc, bc, out, N);
}

// Round 11
// 323.876 us; speedup vs baseline: 2.0893x; 1.0273x over previous
//
#include <hip/hip_runtime.h>

// GCN: 3x (linear -> symmetric-norm conv -> bias -> tanh) -> linear.
// N=200000, E=3200000, F=256->32->16->8->4, fp32.
// Round 11: (a) linear1 v6 — BM=128/BK=16 dbuf, 25KB LDS => 6 blocks/CU
// (24 waves/CU, was 12), grid 1563; (b) csrb at 512 threads (was 256) to
// double per-bucket parallelism (196 blocks only). Rest = round 10.
// Algebra: norm = dinv[s]*dinv[d]  =>  agg_i = dinv_i * (hs_i + sum_in hs_src)
// with hs = (h @ W) * dinv folded into the producing kernel's epilogue.

constexpr int F_IN = 256;
constexpr int BSH = 10;            // nodes per coarse bucket = 1024
constexpr int BN  = 1 << BSH;
constexpr int CH  = 8192;          // edges per chunk
constexpr int SRC_BITS = 18;       // N=200000 < 2^18
constexpr int SRC_MASK = (1 << SRC_BITS) - 1;

// ---- pass A1: per-chunk bucket histogram (transposed store: hist[b][c]) ----
__global__ void histc_kernel(const int* __restrict__ dst, int* __restrict__ hist,
                             int NB_C, int nch, int E) {
    __shared__ int h[256];
    const int t = threadIdx.x, c = blockIdx.x;
    h[t] = 0; __syncthreads();
    const int e0 = c * CH, e1 = min(e0 + CH, E);
    for (int e = e0 + t; e < e1; e += 256)
        atomicAdd(&h[dst[e] >> BSH], 1);
    __syncthreads();
    if (t < NB_C) hist[(size_t)t * nch + c] = h[t];
}

// ---- pass A2: exclusive scan of each bucket row (in place), total -> btotal ----
__global__ void scanb_kernel(int* __restrict__ hist, int* __restrict__ btotal, int nch) {
    __shared__ int s[256];
    const int b = blockIdx.x, t = threadIdx.x;
    int* row = hist + (size_t)b * nch;
    const int K = (nch + 255) / 256;
    int loc[8]; int tot = 0;
    for (int i = 0; i < K; ++i) {
        int idx = t * K + i;
        int v = (idx < nch) ? row[idx] : 0;
        loc[i] = tot; tot += v;
    }
    s[t] = tot; const int own = tot; __syncthreads();
    for (int off = 1; off < 256; off <<= 1) {
        int a = (t >= off) ? s[t - off] : 0; __syncthreads();
        s[t] += a; __syncthreads();
    }
    const int excl = s[t] - own;
    for (int i = 0; i < K; ++i) {
        int idx = t * K + i;
        if (idx < nch) row[idx] = excl + loc[i];
    }
    if (t == 255) btotal[b] = s[255];
}

// ---- pass A3: exclusive scan of bucket totals -> colbase[NB_C+1] ----
__global__ void scanc_kernel(const int* __restrict__ btotal, int* __restrict__ colbase, int NB_C) {
    __shared__ int s[256];
    const int t = threadIdx.x;
    int v = (t < NB_C) ? btotal[t] : 0;
    s[t] = v; const int own = v; __syncthreads();
    for (int off = 1; off < 256; off <<= 1) {
        int a = (t >= off) ? s[t - off] : 0; __syncthreads();
        s[t] += a; __syncthreads();
    }
    if (t < NB_C) colbase[t] = s[t] - own;
    if (t == 255) colbase[NB_C] = s[255];
}

// ---- pass A4: scatter packed (local_dst<<18)|src to exact slots ----
__global__ void scat_kernel(const int* __restrict__ src, const int* __restrict__ dst,
                            const int* __restrict__ hist, const int* __restrict__ colbase,
                            int* __restrict__ pairs, int NB_C, int nch, int E) {
    __shared__ int cur[256];
    const int t = threadIdx.x, c = blockIdx.x;
    if (t < NB_C) cur[t] = colbase[t] + hist[(size_t)t * nch + c];
    __syncthreads();
    const int e0 = c * CH, e1 = min(e0 + CH, E);
    for (int e = e0 + t; e < e1; e += 256) {
        int d = dst[e];
        int b = d >> BSH;
        int p = atomicAdd(&cur[b], 1);
        pairs[p] = ((d & (BN - 1)) << SRC_BITS) | src[e];
    }
}

// ---- pass B: per-bucket CSR build, 512 threads (block = 1024-node bucket) ----
__global__ __launch_bounds__(512) void csrb_kernel(const int* __restrict__ pairs,
                                                   const int* __restrict__ colbase,
                                                   int* __restrict__ cnt, int* __restrict__ rowptr,
                                                   float* __restrict__ dinv, int* __restrict__ list,
                                                   int N) {
    __shared__ int deg[BN];
    __shared__ int lex[BN];
    __shared__ int s[512];
    const int b = blockIdx.x, t = threadIdx.x;
    const int n0 = b << BSH;
    const int g0 = colbase[b], g1 = colbase[b + 1];
    for (int i = t; i < BN; i += 512) deg[i] = 0;
    __syncthreads();
    for (int i = g0 + t; i < g1; i += 512)
        atomicAdd(&deg[pairs[i] >> SRC_BITS], 1);
    __syncthreads();
    const int b2 = t * 2;
    const int l0 = deg[b2], l1 = deg[b2 + 1];
    const int tot = l0 + l1;
    s[t] = tot; const int own = tot; __syncthreads();
    for (int off = 1; off < 512; off <<= 1) {
        int a = (t >= off) ? s[t - off] : 0; __syncthreads();
        s[t] += a; __syncthreads();
    }
    const int excl = s[t] - own;
    lex[b2] = excl; lex[b2 + 1] = excl + l0;
#pragma unroll
    for (int k = 0; k < 2; ++k) {
        int n = n0 + b2 + k;
        if (n < N) {
            int dg = deg[b2 + k];
            cnt[n] = dg;
            rowptr[n] = g0 + lex[b2 + k];
            dinv[n] = rsqrtf((float)dg + 1.0f);
        }
    }
    __syncthreads();
    for (int i = t; i < BN; i += 512) deg[i] = 0;   // reuse as cursors
    __syncthreads();
    for (int i = g0 + t; i < g1; i += 512) {
        int pr = pairs[i];
        int ld = pr >> SRC_BITS;
        int p = lex[ld] + atomicAdd(&deg[ld], 1);
        list[g0 + p] = pr & SRC_MASK;
    }
}

// ---------------- layer-1 GEMM: out = (x @ W) * dinv, K=256, D=32 ----------------
// v6: BM=128 rows, 256 threads, 2x8 thread tile (rows rg, rg+64; cols cg*8..+7).
// BK=16 single-barrier dbuf (issue next -> compute -> write other -> sync).
// LDS 25KB -> 6 blocks/CU (24 waves/CU); grid 1563 = 6.1 blocks/CU.
__global__ __launch_bounds__(256) void linear1_kernel(const float* __restrict__ x,
                                                      const float* __restrict__ W,
                                                      const float* __restrict__ dinv,
                                                      float* __restrict__ out, int N) {
    __shared__ float xs[2][128][20];   // 20 KB
    __shared__ float Wk[2][16][36];    // 4.5 KB
    const int t = threadIdx.x;
    const int rg = t >> 2;             // 0..63 : compute rows rg, rg+64
    const int cg = t & 3;              // cols cg*8..+7
    const int sr = t >> 2;             // staging row sr (and sr+64)
    const int f  = t & 3;              // staging 16B slot within 64B row chunk
    const long row0 = (long)blockIdx.x * 128;

    float4 xst[2];
    float4 wst;
    float acc[2][8] = {};

    auto issue = [&](int kc) {
#pragma unroll
        for (int i = 0; i < 2; ++i) {
            const long gr = row0 + sr + 64 * i;
            xst[i] = (gr < N) ? *(const float4*)(x + gr * F_IN + kc * 16 + f * 4)
                              : make_float4(0.f, 0.f, 0.f, 0.f);
        }
        if (t < 128) wst = *(const float4*)(W + kc * 512 + t * 4);
    };
    auto write_buf = [&](int p) {
#pragma unroll
        for (int i = 0; i < 2; ++i)
            *(float4*)&xs[p][sr + 64 * i][f * 4] = xst[i];
        if (t < 128) {
            const int w = t * 4;
            *(float4*)&Wk[p][w >> 5][w & 31] = wst;
        }
    };

    issue(0);
    write_buf(0);
    __syncthreads();

    int p = 0;
    for (int kc = 0; kc < 16; ++kc, p ^= 1) {
        if (kc < 15) issue(kc + 1);          // loads in flight during compute
#pragma unroll
        for (int k4 = 0; k4 < 4; ++k4) {
            float4 xr[2];
#pragma unroll
            for (int i = 0; i < 2; ++i) xr[i] = *(float4*)&xs[p][rg + 64 * i][k4 * 4];
#pragma unroll
            for (int j = 0; j < 4; ++j) {
                const int kk = k4 * 4 + j;
                const float4 w0 = *(float4*)&Wk[p][kk][cg * 8];
                const float4 w1 = *(float4*)&Wk[p][kk][cg * 8 + 4];
#pragma unroll
                for (int i = 0; i < 2; ++i) {
                    const float xv = (j == 0) ? xr[i].x : (j == 1) ? xr[i].y
                                   : (j == 2) ? xr[i].z : xr[i].w;
                    acc[i][0] += xv * w0.x; acc[i][1] += xv * w0.y;
                    acc[i][2] += xv * w0.z; acc[i][3] += xv * w0.w;
                    acc[i][4] += xv * w1.x; acc[i][5] += xv * w1.y;
                    acc[i][6] += xv * w1.z; acc[i][7] += xv * w1.w;
                }
            }
        }
        if (kc < 15) write_buf(p ^ 1);       // safe: readers are on buf[p]
        __syncthreads();
    }
#pragma unroll
    for (int i = 0; i < 2; ++i) {
        const long r = row0 + rg + 64 * i;
        if (r >= N) continue;
        const float dv = dinv[r];
        float4 o0 = make_float4(acc[i][0] * dv, acc[i][1] * dv, acc[i][2] * dv, acc[i][3] * dv);
        float4 o1 = make_float4(acc[i][4] * dv, acc[i][5] * dv, acc[i][6] * dv, acc[i][7] * dv);
        *(float4*)(out + r * 32 + cg * 8) = o0;
        *(float4*)(out + r * 32 + cg * 8 + 4) = o1;
    }
}

// ---- gather D=32 + fused linear2: out = (tanh(dinv*(hs_i+sum)+b1) @ W2) * dinv ----
__global__ void gather32_lin2_kernel(const int* __restrict__ rowptr, const int* __restrict__ cnt,
                                     const int* __restrict__ list, const float* __restrict__ hs,
                                     const float* __restrict__ dinv, const float* __restrict__ b1,
                                     const float* __restrict__ W2, float* __restrict__ out, int N) {
    __shared__ float W2s[32][16];
    const int t = threadIdx.x;
    if (t < 128) ((float4*)&W2s[0][0])[t] = ((const float4*)W2)[t];
    __syncthreads();
    const int g = t >> 3, lane = t & 7;
    long node = (long)blockIdx.x * 32 + g;
    if (node >= N) return;
    const int start = rowptr[node];
    const int num = cnt[node];
    const int* __restrict__ lp = list + start;
    const float4* __restrict__ hs4 = (const float4*)hs;
    float4 acc = hs4[node * 8 + lane];
    int j = 0;
    for (; j + 8 <= num; j += 8) {
        int s0 = lp[j], s1 = lp[j + 1], s2 = lp[j + 2], s3 = lp[j + 3];
        int s4 = lp[j + 4], s5 = lp[j + 5], s6 = lp[j + 6], s7 = lp[j + 7];
        float4 v0 = hs4[(long)s0 * 8 + lane], v1 = hs4[(long)s1 * 8 + lane];
        float4 v2 = hs4[(long)s2 * 8 + lane], v3 = hs4[(long)s3 * 8 + lane];
        float4 v4 = hs4[(long)s4 * 8 + lane], v5 = hs4[(long)s5 * 8 + lane];
        float4 v6 = hs4[(long)s6 * 8 + lane], v7 = hs4[(long)s7 * 8 + lane];
        acc.x += ((v0.x + v1.x) + (v2.x + v3.x)) + ((v4.x + v5.x) + (v6.x + v7.x));
        acc.y += ((v0.y + v1.y) + (v2.y + v3.y)) + ((v4.y + v5.y) + (v6.y + v7.y));
        acc.z += ((v0.z + v1.z) + (v2.z + v3.z)) + ((v4.z + v5.z) + (v6.z + v7.z));
        acc.w += ((v0.w + v1.w) + (v2.w + v3.w)) + ((v4.w + v5.w) + (v6.w + v7.w));
    }
    for (; j < num; ++j) {
        int s = lp[j];
        float4 v = hs4[(long)s * 8 + lane];
        acc.x += v.x; acc.y += v.y; acc.z += v.z; acc.w += v.w;
    }
    const float dv = dinv[node];
    const float4 bb = *(const float4*)(b1 + lane * 4);
    float4 h;
    h.x = tanhf(acc.x * dv + bb.x);
    h.y = tanhf(acc.y * dv + bb.y);
    h.z = tanhf(acc.z * dv + bb.z);
    h.w = tanhf(acc.w * dv + bb.w);
    const int c0 = lane * 2;
    float o0 = 0.f, o1 = 0.f;
#pragma unroll
    for (int gk = 0; gk < 8; ++gk) {
        const float a0 = __shfl(h.x, gk, 8);
        const float a1 = __shfl(h.y, gk, 8);
        const float a2 = __shfl(h.z, gk, 8);
        const float a3 = __shfl(h.w, gk, 8);
        o0 += a0 * W2s[gk * 4 + 0][c0] + a1 * W2s[gk * 4 + 1][c0]
            + a2 * W2s[gk * 4 + 2][c0] + a3 * W2s[gk * 4 + 3][c0];
        o1 += a0 * W2s[gk * 4 + 0][c0 + 1] + a1 * W2s[gk * 4 + 1][c0 + 1]
            + a2 * W2s[gk * 4 + 2][c0 + 1] + a3 * W2s[gk * 4 + 3][c0 + 1];
    }
    *(float2*)(out + node * 16 + c0) = make_float2(o0 * dv, o1 * dv);
}

// ---- gather D=16 + fused linear3: 4 lanes/node, width-4 shuffles, W3[16][8] ----
__global__ void gather16_lin3_kernel(const int* __restrict__ rowptr, const int* __restrict__ cnt,
                                     const int* __restrict__ list, const float* __restrict__ hs,
                                     const float* __restrict__ dinv, const float* __restrict__ b2,
                                     const float* __restrict__ W3, float* __restrict__ out, int N) {
    __shared__ float W3s[16][8];
    const int t = threadIdx.x;
    if (t < 32) ((float4*)&W3s[0][0])[t] = ((const float4*)W3)[t];
    __syncthreads();
    const int g = t >> 2, lane = t & 3;
    long node = (long)blockIdx.x * 64 + g;
    if (node >= N) return;
    const int start = rowptr[node];
    const int num = cnt[node];
    const int* __restrict__ lp = list + start;
    const float4* __restrict__ hs4 = (const float4*)hs;
    float4 acc = hs4[node * 4 + lane];
    int j = 0;
    for (; j + 8 <= num; j += 8) {
        int s0 = lp[j], s1 = lp[j + 1], s2 = lp[j + 2], s3 = lp[j + 3];
        int s4 = lp[j + 4], s5 = lp[j + 5], s6 = lp[j + 6], s7 = lp[j + 7];
        float4 v0 = hs4[(long)s0 * 4 + lane], v1 = hs4[(long)s1 * 4 + lane];
        float4 v2 = hs4[(long)s2 * 4 + lane], v3 = hs4[(long)s3 * 4 + lane];
        float4 v4 = hs4[(long)s4 * 4 + lane], v5 = hs4[(long)s5 * 4 + lane];
        float4 v6 = hs4[(long)s6 * 4 + lane], v7 = hs4[(long)s7 * 4 + lane];
        acc.x += ((v0.x + v1.x) + (v2.x + v3.x)) + ((v4.x + v5.x) + (v6.x + v7.x));
        acc.y += ((v0.y + v1.y) + (v2.y + v3.y)) + ((v4.y + v5.y) + (v6.y + v7.y));
        acc.z += ((v0.z + v1.z) + (v2.z + v3.z)) + ((v4.z + v5.z) + (v6.z + v7.z));
        acc.w += ((v0.w + v1.w) + (v2.w + v3.w)) + ((v4.w + v5.w) + (v6.w + v7.w));
    }
    for (; j < num; ++j) {
        int s = lp[j];
        float4 v = hs4[(long)s * 4 + lane];
        acc.x += v.x; acc.y += v.y; acc.z += v.z; acc.w += v.w;
    }
    const float dv = dinv[node];
    const float4 bb = *(const float4*)(b2 + lane * 4);
    float4 h;
    h.x = tanhf(acc.x * dv + bb.x);
    h.y = tanhf(acc.y * dv + bb.y);
    h.z = tanhf(acc.z * dv + bb.z);
    h.w = tanhf(acc.w * dv + bb.w);
    const int c0 = lane * 2;
    float o0 = 0.f, o1 = 0.f;
#pragma unroll
    for (int gk = 0; gk < 4; ++gk) {
        const float a0 = __shfl(h.x, gk, 4);
        const float a1 = __shfl(h.y, gk, 4);
        const float a2 = __shfl(h.z, gk, 4);
        const float a3 = __shfl(h.w, gk, 4);
        o0 += a0 * W3s[gk * 4 + 0][c0] + a1 * W3s[gk * 4 + 1][c0]
            + a2 * W3s[gk * 4 + 2][c0] + a3 * W3s[gk * 4 + 3][c0];
        o1 += a0 * W3s[gk * 4 + 0][c0 + 1] + a1 * W3s[gk * 4 + 1][c0 + 1]
            + a2 * W3s[gk * 4 + 2][c0 + 1] + a3 * W3s[gk * 4 + 3][c0 + 1];
    }
    *(float2*)(out + node * 8 + c0) = make_float2(o0 * dv, o1 * dv);
}

// ---------------- D=8 gather fused with classifier ----------------
__global__ void gather8_final_kernel(const int* __restrict__ rowptr, const int* __restrict__ cnt,
                                     const int* __restrict__ list, const float* __restrict__ hs,
                                     const float* __restrict__ dinv, const float* __restrict__ b,
                                     const float* __restrict__ Wc, const float* __restrict__ bc,
                                     float* __restrict__ out, int N) {
    const int t = threadIdx.x;
    const int g = t >> 1, lane = t & 1;
    long node = (long)blockIdx.x * 128 + g;
    if (node >= N) return;
    const int start = rowptr[node];
    const int num = cnt[node];
    const int* __restrict__ lp = list + start;
    const float4* __restrict__ hs4 = (const float4*)hs;
    float4 acc = hs4[node * 2 + lane];
    int j = 0;
    for (; j + 8 <= num; j += 8) {
        int s0 = lp[j], s1 = lp[j + 1], s2 = lp[j + 2], s3 = lp[j + 3];
        int s4 = lp[j + 4], s5 = lp[j + 5], s6 = lp[j + 6], s7 = lp[j + 7];
        float4 v0 = hs4[(long)s0 * 2 + lane], v1 = hs4[(long)s1 * 2 + lane];
        float4 v2 = hs4[(long)s2 * 2 + lane], v3 = hs4[(long)s3 * 2 + lane];
        float4 v4 = hs4[(long)s4 * 2 + lane], v5 = hs4[(long)s5 * 2 + lane];
        float4 v6 = hs4[(long)s6 * 2 + lane], v7 = hs4[(long)s7 * 2 + lane];
        acc.x += ((v0.x + v1.x) + (v2.x + v3.x)) + ((v4.x + v5.x) + (v6.x + v7.x));
        acc.y += ((v0.y + v1.y) + (v2.y + v3.y)) + ((v4.y + v5.y) + (v6.y + v7.y));
        acc.z += ((v0.z + v1.z) + (v2.z + v3.z)) + ((v4.z + v5.z) + (v6.z + v7.z));
        acc.w += ((v0.w + v1.w) + (v2.w + v3.w)) + ((v4.w + v5.w) + (v6.w + v7.w));
    }
    for (; j < num; ++j) {
        int s = lp[j];
        float4 v = hs4[(long)s * 2 + lane];
        acc.x += v.x; acc.y += v.y; acc.z += v.z; acc.w += v.w;
    }
    const float dv = dinv[node];
    const float4 bb = *(const float4*)(b + lane * 4);
    float4 h;
    h.x = tanhf(acc.x * dv + bb.x);
    h.y = tanhf(acc.y * dv + bb.y);
    h.z = tanhf(acc.z * dv + bb.z);
    h.w = tanhf(acc.w * dv + bb.w);
    const float4 w0 = *(const float4*)(Wc + (lane * 4 + 0) * 4);
    const float4 w1 = *(const float4*)(Wc + (lane * 4 + 1) * 4);
    const float4 w2 = *(const float4*)(Wc + (lane * 4 + 2) * 4);
    const float4 w3 = *(const float4*)(Wc + (lane * 4 + 3) * 4);
    float4 p;
    p.x = h.x * w0.x + h.y * w1.x + h.z * w2.x + h.w * w3.x;
    p.y = h.x * w0.y + h.y * w1.y + h.z * w2.y + h.w * w3.y;
    p.z = h.x * w0.z + h.y * w1.z + h.z * w2.z + h.w * w3.z;
    p.w = h.x * w0.w + h.y * w1.w + h.z * w2.w + h.w * w3.w;
    p.x += __shfl_xor(p.x, 1);
    p.y += __shfl_xor(p.y, 1);
    p.z += __shfl_xor(p.z, 1);
    p.w += __shfl_xor(p.w, 1);
    if (lane == 0) {
        const float4 bcv = *(const float4*)bc;
        float4 o = make_float4(p.x + bcv.x, p.y + bcv.y, p.z + bcv.z, p.w + bcv.w);
        *(float4*)(out + node * 4) = o;
    }
}

extern "C" void kernel_launch(void* const* d_in, const int* in_sizes, int n_in,
                              void* d_out, int out_size, void* d_ws, size_t ws_size,
                              hipStream_t stream) {
    const float* x  = (const float*)d_in[0];
    const int*   ei = (const int*)d_in[1];
    const float* W1 = (const float*)d_in[2];
    const float* b1 = (const float*)d_in[3];
    const float* W2 = (const float*)d_in[4];
    const float* b2 = (const float*)d_in[5];
    const float* W3 = (const float*)d_in[6];
    const float* b3 = (const float*)d_in[7];
    const float* Wc = (const float*)d_in[8];
    const float* bc = (const float*)d_in[9];
    float* out = (float*)d_out;

    const int N = in_sizes[0] / F_IN;
    const int E = in_sizes[1] / 2;
    const int* src = ei;
    const int* dst = ei + E;
    const int B = 256;

    const int NB_C = (N + BN - 1) >> BSH;       // coarse buckets (196) <= 256
    const int nch  = (E + CH - 1) / CH;         // chunks (391)

    char* p = (char*)d_ws;
    auto take = [&](size_t bytes) { char* q = p; p += (bytes + 255) & ~size_t(255); return q; };
    int*   cnt     = (int*)take((size_t)N * 4);
    int*   rowptr  = (int*)take((size_t)N * 4);
    float* dinv    = (float*)take((size_t)N * 4);
    int*   hist    = (int*)take((size_t)NB_C * nch * 4);
    int*   btotal  = (int*)take((size_t)NB_C * 4);
    int*   colbase = (int*)take((size_t)(NB_C + 1) * 4);
    int*   list    = (int*)take((size_t)E * 4);
    float* bufA    = (float*)take((size_t)N * 32 * 4);
    float* bufB    = (float*)take((size_t)N * 32 * 4);
    int*   pairs   = (int*)bufA;   // alias: pairs dead before linear1 writes bufA

    // ---- CSR build (deterministic two-level counting sort, packed pairs) ----
    histc_kernel<<<nch, B, 0, stream>>>(dst, hist, NB_C, nch, E);
    scanb_kernel<<<NB_C, B, 0, stream>>>(hist, btotal, nch);
    scanc_kernel<<<1, B, 0, stream>>>(btotal, colbase, NB_C);
    scat_kernel<<<nch, B, 0, stream>>>(src, dst, hist, colbase, pairs, NB_C, nch, E);
    csrb_kernel<<<NB_C, 512, 0, stream>>>(pairs, colbase, cnt, rowptr, dinv, list, N);

    // ---- layer 1: 256 -> 32 ----
    linear1_kernel<<<(N + 127) / 128, B, 0, stream>>>(x, W1, dinv, bufA, N);
    // ---- layer 1 conv + layer 2 linear fused ----
    gather32_lin2_kernel<<<(N + 31) / 32, B, 0, stream>>>(rowptr, cnt, list, bufA, dinv, b1, W2, bufB, N);
    // ---- layer 2 conv + layer 3 linear fused ----
    gather16_lin3_kernel<<<(N + 63) / 64, B, 0, stream>>>(rowptr, cnt, list, bufB, dinv, b2, W3, bufA, N);
    // ---- layer 3 conv + classifier fused ----
    gather8_final_kernel<<<(N + 127) / 128, B, 0, stream>>>(rowptr, cnt, list, bufA, dinv, b3, Wc, bc, out, N);
}